// Round 4
// baseline (483.288 us; speedup 1.0000x reference)
//
#include <hip/hip_runtime.h>

// ---------------------------------------------------------------------------
// GraphGridCrossAttnModel — round 4: reg-resident Pk, bf16 intermediates,
// kernel fusion (9 dispatches).
// B=4 T=24 N=2048 DG=64 E=128 NH=4 HD=32 H=W=64 P=8 -> NP=64
// MFMA layout (16x16x32 bf16, m89-verified):
//  A: m=l&15, k=(l>>4)*8+j ; B: n=l&15, k=(l>>4)*8+j ; D: col=l&15, row=(l>>4)*4+reg
// ---------------------------------------------------------------------------

typedef unsigned short u16;
using bf8 = __attribute__((ext_vector_type(8))) short;
using f4v = __attribute__((ext_vector_type(4))) float;
#define MFMA16(a, b, c) __builtin_amdgcn_mfma_f32_16x16x32_bf16(a, b, c, 0, 0, 0)

constexpr float INV_SCALE = 0.17677669529663687f;   // 1/sqrt(32)

__device__ __forceinline__ u16 f2bf(float f) {
  unsigned u = __float_as_uint(f);
  u += 0x7FFFu + ((u >> 16) & 1u);
  return (u16)(u >> 16);
}
__device__ __forceinline__ unsigned pk2(float a, float b) {
  return (unsigned)f2bf(a) | ((unsigned)f2bf(b) << 16);
}
__device__ __forceinline__ float bflo(unsigned v) {          // low bf16 -> f32
  return __uint_as_float(v << 16);
}
__device__ __forceinline__ float bfhi(unsigned v) {          // high bf16 -> f32
  return __uint_as_float(v & 0xffff0000u);
}

// ---------------- fused precompute: w1c | cvt | teq | fold -------------------

__global__ __launch_bounds__(128) void k_pre1(
    const float* gk_w1, const float* gv_w1, const float* rk_w1, const float* rv_w1,
    u16* W1c_g, u16* W1c_r,
    const float* pe_w, u16* peB,
    const float* tidx, const float* te_w1, const float* te_b1,
    const float* te_w2, const float* te_b2,
    const float* wg, const float* bg, const float* wr, const float* br,
    float* qg, float* qr,
    const float* A0, const float* Ab0, const float* B0, const float* Bb0, float* O0, float* Ob0,
    const float* A1, const float* Ab1, const float* B1, const float* Bb1, float* O1, float* Ob1,
    const float* A2, const float* Ab2, const float* B2, const float* Bb2, float* O2, float* Ob2,
    const float* A3, const float* Ab3, const float* B3, const float* Bb3, float* O3, float* Ob3) {
  int x = blockIdx.x, e = threadIdx.x;
  __shared__ float sh[256];
  if (x < 512) {                    // --- W1c bf16 transpose-pack
    int c = x & 255, brn = x >> 8;
    int DIN = brn ? 128 : 64;
    if (e < DIN) {
      const float* src = brn ? (c < 128 ? rk_w1 : rv_w1) : (c < 128 ? gk_w1 : gv_w1);
      u16* dst = brn ? W1c_r : W1c_g;
      dst[c * DIN + e] = f2bf(src[e * 128 + (c & 127)]);
    }
  } else if (x < 1536) {            // --- pe_w -> bf16
    int i = ((x - 512) * 128 + e) * 8;
    float4 v0 = *(const float4*)(pe_w + i);
    float4 v1 = *(const float4*)(pe_w + i + 4);
    uint4 o; o.x = pk2(v0.x, v0.y); o.y = pk2(v0.z, v0.w);
    o.z = pk2(v1.x, v1.y); o.w = pk2(v1.z, v1.w);
    *(uint4*)&peB[i] = o;
  } else if (x < 1632) {            // --- te -> q_g/q_r
    int row = x - 1536;
    float tv = tidx[row];
    sh[e] = fmaxf(tv * te_w1[e] + te_b1[e], 0.f);
    __syncthreads();
    float a = te_b2[e];
    for (int j = 0; j < 128; ++j) a += sh[j] * te_w2[j * 128 + e];
    sh[128 + e] = a;
    __syncthreads();
    float ag = bg[e], ar = br[e];
    for (int j = 0; j < 128; ++j) {
      float xx = sh[128 + j];
      ag += xx * wg[j * 128 + e];
      ar += xx * wr[j * 128 + e];
    }
    qg[row * 128 + e] = ag;
    qr[row * 128 + e] = ar;
  } else {                          // --- fold W2@Wqkv
    int sub = x - 1632;
    int task = sub / 129, j = sub % 129;
    const float *A, *Ab, *Bm, *Bb; float *O, *Ob;
    switch (task) {
      case 0: A=A0; Ab=Ab0; Bm=B0; Bb=Bb0; O=O0; Ob=Ob0; break;
      case 1: A=A1; Ab=Ab1; Bm=B1; Bb=Bb1; O=O1; Ob=Ob1; break;
      case 2: A=A2; Ab=Ab2; Bm=B2; Bb=Bb2; O=O2; Ob=Ob2; break;
      default:A=A3; Ab=Ab3; Bm=B3; Bb=Bb3; O=O3; Ob=Ob3; break;
    }
    sh[e] = (j < 128) ? A[j * 128 + e] : Ab[e];
    __syncthreads();
    float acc = (j < 128) ? 0.f : Bb[e];
    for (int m = 0; m < 128; ++m) acc += sh[m] * Bm[m * 128 + e];
    if (j < 128) O[j * 128 + e] = acc; else Ob[e] = acc;
  }
}

// merged: y<8 -> Wvo/bvo tasks ; y>=8 -> PkT/ck tasks
__global__ __launch_bounds__(128) void k_wvopk(
    const float* Wv_g, const float* bv_g, const float* ow_g, const float* ob_g, float* Wvo_g, float* bvo_g,
    const float* Wv_r, const float* bv_r, const float* ow_r, const float* ob_r, float* Wvo_r, float* bvo_r,
    const float* Wk_g, const float* bk_g, const float* q_g, u16* PkT_g, float* ck_g,
    const float* Wk_r, const float* bk_r, const float* q_r, u16* PkT_r, float* ck_r) {
  int j = blockIdx.x, e = threadIdx.x;
  if (blockIdx.y < 8) {
    int br = blockIdx.y >> 2, h = blockIdx.y & 3;
    const float* Wv = br ? Wv_r : Wv_g;  const float* bv = br ? bv_r : bv_g;
    const float* ow = br ? ow_r : ow_g;  const float* ob = br ? ob_r : ob_g;
    float* Wvo = br ? Wvo_r : Wvo_g;     float* bvo = br ? bvo_r : bvo_g;
    if (j < 128) {
      __shared__ float wrow[32];
      if (e < 32) wrow[e] = Wv[j * 128 + h * 32 + e];
      __syncthreads();
      float acc = 0.f;
      for (int d = 0; d < 32; ++d) acc += wrow[d] * ow[(h * 32 + d) * 128 + e];
      Wvo[(h * 128 + j) * 128 + e] = acc;
    } else if (h == 0) {
      __shared__ float bbv[128];
      bbv[e] = bv[e];
      __syncthreads();
      float acc = ob[e];
      for (int m = 0; m < 128; ++m) acc += bbv[m] * ow[m * 128 + e];
      bvo[e] = acc;
    }
  } else {
    int y = blockIdx.y - 8;
    int br = y >> 2, b = y & 3;
    int hq = e;
    if (hq >= 96) return;
    const float* Wk = br ? Wk_r : Wk_g;  const float* bk = br ? bk_r : bk_g;
    const float* q  = br ? q_r  : q_g;
    u16* PkT = br ? PkT_r : PkT_g;       float* ck = br ? ck_r : ck_g;
    int h = hq / 24, t = hq % 24;
    const float* qrow = q + (b * 24 + t) * 128 + h * 32;
    if (j < 128) {
      const float* wrow = Wk + j * 128 + h * 32;
      float acc = 0.f;
      for (int d = 0; d < 32; ++d) acc += wrow[d] * qrow[d];
      PkT[((size_t)b * 96 + hq) * 136 + j] = f2bf(acc * INV_SCALE);
    } else {
      float acc = 0.f;
      for (int d = 0; d < 32; ++d) acc += bk[h * 32 + d] * qrow[d];
      ck[b * 96 + hq] = acc * INV_SCALE;
    }
  }
}

// ---------------- fused flash attention, bf16 MFMA ---------------------------
// 4 waves/block; 64-key tiles; Xt double-buffered; Pk held in 96 VGPRs.

template <int DIN, int NRED, bool INBF>
__global__ __launch_bounds__(256, 2) void k_flash(
    const void* __restrict__ Xv, const float* __restrict__ redbias, size_t rstride,
    const u16* __restrict__ W1c,            // [256][DIN] bf16 (k cols | v cols)
    const float* __restrict__ b1k, const float* __restrict__ b1v,
    const u16* __restrict__ PkT,            // [b][96][136] bf16
    const float* __restrict__ ck,           // [b][96]
    u16* __restrict__ accP, float* __restrict__ lP,
    int KL, int kpb) {
  constexpr int KS = DIN / 32;
  constexpr int PD = DIN + 8;
  constexpr int PH = 136, PV = 72, PP = 72;
  constexpr int NR = DIN / 16;              // 4-elem loads per thread per tile
  int b = blockIdx.y, chunk = blockIdx.x, nchunk = gridDim.x;
  int t = threadIdx.x;
  int l = t & 63, w = t >> 6;
  int l16 = l & 15, l4 = l >> 4;

  __shared__ __align__(16) u16 Xt[2][64 * PD];
  __shared__ __align__(16) u16 HB[9216];        // Hk[64][136] / HvT[128][72]
  __shared__ __align__(16) u16 Pt[96 * PP];
  __shared__ float lred[384];

  size_t xbase = (size_t)b * KL * DIN + (size_t)chunk * kpb * DIN;

  // Pk fragments in registers (24 x bf8 = 96 VGPR), loaded once from global
  bf8 bp[4][6];
#pragma unroll
  for (int ks = 0; ks < 4; ++ks)
#pragma unroll
    for (int n = 0; n < 6; ++n)
      bp[ks][n] = *(const bf8*)(PkT + ((size_t)b * 96 + n * 16 + l16) * 136 + ks * 32 + l4 * 8);

  bf8 wkA[2][KS], wvB[2][KS];
#pragma unroll
  for (int m = 0; m < 2; ++m)
#pragma unroll
    for (int ks = 0; ks < KS; ++ks) {
      int hid = w * 32 + m * 16 + l16;
      wkA[m][ks] = *(const bf8*)(W1c + (size_t)hid * DIN + ks * 32 + l4 * 8);
      wvB[m][ks] = *(const bf8*)(W1c + (size_t)(128 + hid) * DIN + ks * 32 + l4 * 8);
    }
  float bkA[2][4], bvB[2], ckr[6];
#pragma unroll
  for (int m = 0; m < 2; ++m)
#pragma unroll
    for (int r = 0; r < 4; ++r) bkA[m][r] = b1k[w * 32 + m * 16 + l4 * 4 + r];
#pragma unroll
  for (int n = 0; n < 2; ++n) bvB[n] = b1v[w * 32 + n * 16 + l16];
#pragma unroll
  for (int n = 0; n < 6; ++n) ckr[n] = ck[b * 96 + n * 16 + l16];

  f4v accO[6][2];
#pragma unroll
  for (int m = 0; m < 6; ++m)
#pragma unroll
    for (int n = 0; n < 2; ++n) accO[m][n] = (f4v){0.f, 0.f, 0.f, 0.f};
  float lacc[6] = {0.f, 0.f, 0.f, 0.f, 0.f, 0.f};

  float4 xr[NR];
  auto load_tile = [&](int kt) {
#pragma unroll
    for (int r = 0; r < NR; ++r) {
      int idx = (r * 256 + t) * 4;
      if constexpr (!INBF) {
        const float* Xrow = (const float*)Xv + xbase + (size_t)kt * 64 * DIN;
        xr[r] = *(const float4*)(Xrow + idx);
      } else {
        const u16* Xrow = (const u16*)Xv + xbase + (size_t)kt * 64 * DIN;
        int din = idx % DIN;
        float4 a = *(const float4*)(redbias + din);
#pragma unroll
        for (int c = 0; c < NRED; ++c) {
          uint2 v = *(const uint2*)(Xrow + (size_t)c * rstride + idx);
          a.x += bflo(v.x); a.y += bfhi(v.x);
          a.z += bflo(v.y); a.w += bfhi(v.y);
        }
        xr[r] = a;
      }
    }
  };

  int ntile = kpb >> 6;
  load_tile(0);
  int buf = 0;
  for (int kt = 0; kt < ntile; ++kt) {
    // ---- write staged tile (regs -> LDS bf16), prefetch next ----
#pragma unroll
    for (int r = 0; r < NR; ++r) {
      int idx = (r * 256 + t) * 4;
      int key = idx / DIN, din = idx % DIN;
      uint2 o; o.x = pk2(xr[r].x, xr[r].y); o.y = pk2(xr[r].z, xr[r].w);
      *(uint2*)&Xt[buf][key * PD + din] = o;
    }
    if (kt + 1 < ntile) load_tile(kt + 1);
    __syncthreads();                                   // b1

    // ---- G1a: Hk = W1k^T @ X^T ----
    {
      f4v hk[2][4];
#pragma unroll
      for (int m = 0; m < 2; ++m)
#pragma unroll
        for (int n = 0; n < 4; ++n) hk[m][n] = (f4v){0.f, 0.f, 0.f, 0.f};
#pragma unroll
      for (int ks = 0; ks < KS; ++ks) {
        bf8 xf[4];
#pragma unroll
        for (int n = 0; n < 4; ++n)
          xf[n] = *(const bf8*)&Xt[buf][(n * 16 + l16) * PD + ks * 32 + l4 * 8];
#pragma unroll
        for (int m = 0; m < 2; ++m)
#pragma unroll
          for (int n = 0; n < 4; ++n) hk[m][n] = MFMA16(wkA[m][ks], xf[n], hk[m][n]);
      }
#pragma unroll
      for (int m = 0; m < 2; ++m)
#pragma unroll
        for (int n = 0; n < 4; ++n) {
          int key = n * 16 + l16;
          int hid0 = w * 32 + m * 16 + l4 * 4;
          float v0 = fmaxf(hk[m][n][0] + bkA[m][0], 0.f);
          float v1 = fmaxf(hk[m][n][1] + bkA[m][1], 0.f);
          float v2 = fmaxf(hk[m][n][2] + bkA[m][2], 0.f);
          float v3 = fmaxf(hk[m][n][3] + bkA[m][3], 0.f);
          uint2 o; o.x = pk2(v0, v1); o.y = pk2(v2, v3);
          *(uint2*)&HB[key * PH + hid0] = o;
        }
    }
    __syncthreads();                                   // b2

    // ---- G2: S = Hk @ Pk (Pk from registers) ----
    {
      f4v sa[6];
#pragma unroll
      for (int n = 0; n < 6; ++n) sa[n] = (f4v){ckr[n], ckr[n], ckr[n], ckr[n]};
#pragma unroll
      for (int ks = 0; ks < 4; ++ks) {
        bf8 a = *(const bf8*)&HB[(w * 16 + l16) * PH + ks * 32 + l4 * 8];
#pragma unroll
        for (int n = 0; n < 6; ++n) sa[n] = MFMA16(a, bp[ks][n], sa[n]);
      }
#pragma unroll
      for (int n = 0; n < 6; ++n) {
        float e0 = __expf(sa[n][0]), e1 = __expf(sa[n][1]);
        float e2 = __expf(sa[n][2]), e3 = __expf(sa[n][3]);
        float ls = (e0 + e1) + (e2 + e3);
        ls += __shfl_xor(ls, 16);
        ls += __shfl_xor(ls, 32);
        lacc[n] += ls;
        uint2 o; o.x = pk2(e0, e1); o.y = pk2(e2, e3);
        *(uint2*)&Pt[(n * 16 + l16) * PP + w * 16 + l4 * 4] = o;
      }
    }
    __syncthreads();                                   // b3 (Hk dead, Pt ready)

    // ---- G1b: Hv = X @ W1v -> HvT[hid][key] ----
    {
      f4v hv[4][2];
#pragma unroll
      for (int m = 0; m < 4; ++m)
#pragma unroll
        for (int n = 0; n < 2; ++n) hv[m][n] = (f4v){0.f, 0.f, 0.f, 0.f};
#pragma unroll
      for (int ks = 0; ks < KS; ++ks) {
        bf8 xa[4];
#pragma unroll
        for (int m = 0; m < 4; ++m)
          xa[m] = *(const bf8*)&Xt[buf][(m * 16 + l16) * PD + ks * 32 + l4 * 8];
#pragma unroll
        for (int m = 0; m < 4; ++m)
#pragma unroll
          for (int n = 0; n < 2; ++n) hv[m][n] = MFMA16(xa[m], wvB[n][ks], hv[m][n]);
      }
#pragma unroll
      for (int m = 0; m < 4; ++m)
#pragma unroll
        for (int n = 0; n < 2; ++n) {
          int d = w * 32 + n * 16 + l16;
          int key0 = m * 16 + l4 * 4;
          float v0 = fmaxf(hv[m][n][0] + bvB[n], 0.f);
          float v1 = fmaxf(hv[m][n][1] + bvB[n], 0.f);
          float v2 = fmaxf(hv[m][n][2] + bvB[n], 0.f);
          float v3 = fmaxf(hv[m][n][3] + bvB[n], 0.f);
          uint2 o; o.x = pk2(v0, v1); o.y = pk2(v2, v3);
          *(uint2*)&HB[d * PV + key0] = o;
        }
    }
    __syncthreads();                                   // b4 (HvT ready)

    // ---- G3: ACC += P^T @ Hv ----
#pragma unroll
    for (int ks = 0; ks < 2; ++ks) {
      bf8 pa[6];
#pragma unroll
      for (int m = 0; m < 6; ++m)
        pa[m] = *(const bf8*)&Pt[(m * 16 + l16) * PP + ks * 32 + l4 * 8];
#pragma unroll
      for (int n = 0; n < 2; ++n) {
        bf8 hb = *(const bf8*)&HB[(w * 32 + n * 16 + l16) * PV + ks * 32 + l4 * 8];
#pragma unroll
        for (int m = 0; m < 6; ++m) accO[m][n] = MFMA16(pa[m], hb, accO[m][n]);
      }
    }
    buf ^= 1;
    // no trailing barrier: next write targets the other Xt buffer; b1 orders HB/Pt.
  }

  // ---- write partial ACC (96x128 bf16) and partial l (96 fp32) ----
  u16* ap = accP + (size_t)(b * nchunk + chunk) * 96 * 128;
#pragma unroll
  for (int m = 0; m < 6; ++m)
#pragma unroll
    for (int n = 0; n < 2; ++n) {
      int d = w * 32 + n * 16 + l16;
#pragma unroll
      for (int r = 0; r < 4; ++r) {
        int hq = m * 16 + l4 * 4 + r;
        ap[hq * 128 + d] = f2bf(accO[m][n][r]);
      }
    }
  if (l4 == 0) {
#pragma unroll
    for (int n = 0; n < 6; ++n) lred[w * 96 + n * 16 + l16] = lacc[n];
  }
  __syncthreads();
  if (t < 96) {
    float s = lred[t] + lred[96 + t] + lred[192 + t] + lred[288 + t];
    lP[(size_t)(b * nchunk + chunk) * 96 + t] = s;
  }
}

// ---------------- patch conv, bf16 MFMA (split-K 8, swizzled Wt) -------------

__global__ __launch_bounds__(256, 3) void k_patch(const float* __restrict__ X,
    const u16* __restrict__ peB, u16* __restrict__ patchP) {
  int bt = blockIdx.x, kc = blockIdx.y;
  int t = threadIdx.x;
  int l = t & 63, w = t >> 6;
  int l16 = l & 15, l4 = l >> 4;
  const float* Xbt = X + (size_t)bt * 524288 + (size_t)kc * 65536;

  __shared__ __align__(16) u16 Xp[64 * 136];
  __shared__ __align__(16) u16 Wt[128 * 128];   // XOR-swizzled: slot ^= co&7

  f4v acc[4][2];
#pragma unroll
  for (int m = 0; m < 4; ++m)
#pragma unroll
    for (int n = 0; n < 2; ++n) acc[m][n] = (f4v){0.f, 0.f, 0.f, 0.f};

  float4 xr[8];
  auto loadX = [&](int s) {
    const float* img = Xbt + (size_t)s * 8192;
#pragma unroll
    for (int r = 0; r < 8; ++r) xr[r] = *(const float4*)(img + (r * 256 + t) * 4);
  };
  loadX(0);

  for (int s = 0; s < 8; ++s) {
#pragma unroll
    for (int r = 0; r < 8; ++r) {
      int idx = (r * 256 + t) * 4;
      int cl = idx >> 12, off = idx & 4095;
      int h = off >> 6, w0 = off & 63;
      int patch = (h >> 3) * 8 + (w0 >> 3);
      int within = (h & 7) * 8 + (w0 & 7);
      uint2 o; o.x = pk2(xr[r].x, xr[r].y); o.y = pk2(xr[r].z, xr[r].w);
      *(uint2*)&Xp[patch * 136 + cl * 64 + within] = o;
    }
    {
      int colbase = kc * 1024 + s * 128;
#pragma unroll
      for (int r = 0; r < 8; ++r) {
        int idx = r * 256 + t;
        int co = idx >> 4, part = idx & 15;
        int slot = part ^ (co & 7);
        uint4 v = *(const uint4*)(peB + (size_t)co * 8192 + colbase + part * 8);
        *(uint4*)&Wt[co * 128 + slot * 8] = v;
      }
    }
    if (s < 7) loadX(s + 1);
    __syncthreads();
#pragma unroll
    for (int ks2 = 0; ks2 < 4; ++ks2) {
      bf8 af[4];
#pragma unroll
      for (int m = 0; m < 4; ++m)
        af[m] = *(const bf8*)&Xp[(m * 16 + l16) * 136 + ks2 * 32 + l4 * 8];
#pragma unroll
      for (int n = 0; n < 2; ++n) {
        int co = w * 32 + n * 16 + l16;
        int slot = (ks2 * 4 + l4) ^ (co & 7);
        bf8 bf_ = *(const bf8*)&Wt[co * 128 + slot * 8];
#pragma unroll
        for (int m = 0; m < 4; ++m) acc[m][n] = MFMA16(af[m], bf_, acc[m][n]);
      }
    }
    __syncthreads();
  }
  u16* outp = patchP + ((size_t)kc * 6144 + bt * 64) * 128;
#pragma unroll
  for (int m = 0; m < 4; ++m)
#pragma unroll
    for (int n = 0; n < 2; ++n) {
      int d = w * 32 + n * 16 + l16;
#pragma unroll
      for (int r = 0; r < 4; ++r) {
        int patch = m * 16 + l4 * 4 + r;
        outp[patch * 128 + d] = f2bf(acc[m][n][r]);
      }
    }
}

// ---------------- merged chunk-reduce + og ----------------------------------
// grid (24, 4): block = (t, b). og[b,t,:] = bvo + sum_h (ACC[b,h,t,:]/l) @ Wvo[h]

__global__ __launch_bounds__(256) void k_ogred(const u16* __restrict__ accP,
    const float* __restrict__ lP, int nchunk,
    const float* __restrict__ Wvo, const float* __restrict__ bvo,
    float* __restrict__ og) {
  int t = blockIdx.x, b = blockIdx.y, tid = threadIdx.x;
  __shared__ float op[512];
  __shared__ float invl[4];
  for (int p = tid; p < 512; p += 256) {
    int h = p >> 7, e = p & 127;
    const u16* src = accP + ((size_t)b * nchunk * 96 + h * 24 + t) * 128 + e;
    float s = 0.f;
    for (int c = 0; c < nchunk; ++c) s += bflo((unsigned)src[(size_t)c * 12288]);
    op[p] = s;
  }
  if (tid < 4) {
    const float* lp = lP + (size_t)b * nchunk * 96 + tid * 24 + t;
    float ls = 0.f;
    for (int c = 0; c < nchunk; ++c) ls += lp[(size_t)c * 96];
    invl[tid] = 1.f / ls;
  }
  __syncthreads();
  for (int p = tid; p < 512; p += 256) op[p] *= invl[p >> 7];
  __syncthreads();
  if (tid < 128) {
    int e = tid;
    float acc = bvo[e];
    for (int h = 0; h < 4; ++h)
      for (int j = 0; j < 128; ++j) acc += op[h * 128 + j] * Wvo[(h * 128 + j) * 128 + e];
    og[(b * 24 + t) * 128 + e] = acc;
  }
}

// U = og_r @ up_w : block owns 64 out-cols, og (48KB) in LDS, up_w read ONCE.
__global__ __launch_bounds__(256) void k_U(const float* __restrict__ og_r,
    const float* __restrict__ up_w, float* __restrict__ U) {
  int col = blockIdx.x * 64 + (threadIdx.x & 63);
  int rg = threadIdx.x >> 6;               // 4 row-groups x 24 rows
  __shared__ float og_s[96 * 128];
  for (int i = threadIdx.x; i < 96 * 128 / 4; i += 256)
    ((float4*)og_s)[i] = ((const float4*)og_r)[i];
  __syncthreads();
  float acc[24];
#pragma unroll
  for (int r = 0; r < 24; ++r) acc[r] = 0.f;
#pragma unroll 4
  for (int c = 0; c < 128; ++c) {
    float wv = up_w[(size_t)c * 8192 + col];
#pragma unroll
    for (int r = 0; r < 24; ++r) acc[r] += og_s[(rg * 24 + r) * 128 + c] * wv;
  }
#pragma unroll
  for (int r = 0; r < 24; ++r) U[(size_t)(rg * 24 + r) * 8192 + col] = acc[r];
}

// ---------------- merged output writer: gout | up ----------------------------

__global__ __launch_bounds__(256) void k_upall(const float* __restrict__ og,
    const float* __restrict__ U, const float* __restrict__ up_b,
    float* __restrict__ outg, float* __restrict__ outu) {
  int x = blockIdx.x;
  if (x < 4096) {                       // ---- g_out lerp writer
    int b = x >> 10;
    const float* ogb = og + b * 3072;
    float* ob = outg + (size_t)b * 6291456;
    for (int i4 = (x & 1023) * 256 + threadIdx.x; i4 < 1572864; i4 += 1024 * 256) {
      int i = i4 * 4;
      int n = i >> 7, e = i & 127;
      float src = fmaxf((n + 0.5f) * (1.f / 2048.f) - 0.5f, 0.f);
      int t0 = (int)src; float lam = src - (float)t0; int t1 = min(t0 + 1, 23);
      float4 a = *(const float4*)&ogb[t0 * 128 + e];
      float4 c = *(const float4*)&ogb[t1 * 128 + e];
      float4 o;
      o.x = a.x + lam * (c.x - a.x); o.y = a.y + lam * (c.y - a.y);
      o.z = a.z + lam * (c.z - a.z); o.w = a.w + lam * (c.w - a.w);
      *(float4*)&ob[i] = o;
    }
  } else {                              // ---- up lerp-upsample writer
    for (int i4 = (x - 4096) * 256 + threadIdx.x; i4 < 12582912; i4 += 4096 * 256) {
      int i = i4 * 4;
      int w0 = i & 63;
      int h  = (i >> 6) & 63;
      int o  = (i >> 12) & 127;
      int bt = i >> 19;                 // 0..95
      int b = bt / 24, tt = bt - b * 24;
      int ii = h >> 3, p = h & 7, j = w0 >> 3, q0 = w0 & 7;
      int n = tt * 64 + ii * 8 + j;
      float src = fmaxf((n + 0.5f) * (1.f / 64.f) - 0.5f, 0.f);
      int t0 = (int)src; float lam = src - (float)t0; int t1 = min(t0 + 1, 23);
      const float* u0 = U + (size_t)(b * 24 + t0) * 8192 + o * 64 + p * 8 + q0;
      const float* u1 = U + (size_t)(b * 24 + t1) * 8192 + o * 64 + p * 8 + q0;
      float bb = up_b[o];
      float4 a = *(const float4*)u0, c = *(const float4*)u1;
      float4 r;
      r.x = a.x + lam * (c.x - a.x) + bb; r.y = a.y + lam * (c.y - a.y) + bb;
      r.z = a.z + lam * (c.z - a.z) + bb; r.w = a.w + lam * (c.w - a.w) + bb;
      *(float4*)&outu[i] = r;
    }
  }
}

// ---------------------------------------------------------------------------

extern "C" void kernel_launch(void* const* d_in, const int* in_sizes, int n_in,
                              void* d_out, int out_size, void* d_ws, size_t ws_size,
                              hipStream_t stream) {
  (void)in_sizes; (void)n_in; (void)out_size; (void)ws_size;
  const float* gf    = (const float*)d_in[0];
  const float* gridf = (const float*)d_in[1];
  const float* gti   = (const float*)d_in[2];
  const float* gek_w1 = (const float*)d_in[4],  *gek_b1 = (const float*)d_in[5];
  const float* gek_w2 = (const float*)d_in[6],  *gek_b2 = (const float*)d_in[7];
  const float* gev_w1 = (const float*)d_in[8],  *gev_b1 = (const float*)d_in[9];
  const float* gev_w2 = (const float*)d_in[10], *gev_b2 = (const float*)d_in[11];
  const float* rk_w1  = (const float*)d_in[12], *rk_b1  = (const float*)d_in[13];
  const float* rk_w2  = (const float*)d_in[14], *rk_b2  = (const float*)d_in[15];
  const float* rv_w1  = (const float*)d_in[16], *rv_b1  = (const float*)d_in[17];
  const float* rv_w2  = (const float*)d_in[18], *rv_b2  = (const float*)d_in[19];
  const float* te_w1  = (const float*)d_in[20], *te_b1  = (const float*)d_in[21];
  const float* te_w2  = (const float*)d_in[22], *te_b2  = (const float*)d_in[23];
  const float* pe_w   = (const float*)d_in[24], *pe_b   = (const float*)d_in[25];
  const float* up_w   = (const float*)d_in[26], *up_b   = (const float*)d_in[27];
  const float* ag_q_w = (const float*)d_in[28], *ag_q_b = (const float*)d_in[29];
  const float* ag_k_w = (const float*)d_in[30], *ag_k_b = (const float*)d_in[31];
  const float* ag_v_w = (const float*)d_in[32], *ag_v_b = (const float*)d_in[33];
  const float* ag_o_w = (const float*)d_in[34], *ag_o_b = (const float*)d_in[35];
  const float* ar_q_w = (const float*)d_in[36], *ar_q_b = (const float*)d_in[37];
  const float* ar_k_w = (const float*)d_in[38], *ar_k_b = (const float*)d_in[39];
  const float* ar_v_w = (const float*)d_in[40], *ar_v_b = (const float*)d_in[41];
  const float* ar_o_w = (const float*)d_in[42], *ar_o_b = (const float*)d_in[43];

  float* out = (float*)d_out;          // g_out (25165824 f) then up (50331648 f)
  float* ws = (float*)d_ws;
  size_t off = 0;
  auto A = [&](size_t n) { float* p = ws + off; off += n; return p; };
  float* q_g   = A(12288);   float* q_r   = A(12288);
  float* Wk_g  = A(16384);   float* bk_g  = A(128);
  float* Wv_g  = A(16384);   float* bv_g  = A(128);
  float* Wk_r  = A(16384);   float* bk_r  = A(128);
  float* Wv_r  = A(16384);   float* bv_r  = A(128);
  float* Wvo_g = A(65536);   float* bvo_g = A(128);
  float* Wvo_r = A(65536);   float* bvo_r = A(128);
  float* ck_g  = A(384);     float* ck_r  = A(384);
  u16*   PkT_g = (u16*)A(26112);   // 4*96*136 bf16
  u16*   PkT_r = (u16*)A(26112);
  u16*   W1c_g = (u16*)A(8192);    // 256*64 bf16
  u16*   W1c_r = (u16*)A(16384);   // 256*128 bf16
  u16*   peB   = (u16*)A(524288);  // 128*8192 bf16
  float* lP_g  = A(49152);   float* lP_r  = A(9216);
  float* og_g  = A(12288);   float* og_r  = A(12288);
  u16*   accP_g = (u16*)A(3145728);   // 4*128*12288 bf16
  u16*   patchP = (u16*)A(3145728);   // 8*6144*128 bf16
  u16*   accP_r = (u16*)A(589824);    // 4*24*12288 bf16
  float* U      = A(786432);
  // total ~8.6M floats (~34 MB)

  k_pre1<<<2148, 128, 0, stream>>>(
      gek_w1, gev_w1, rk_w1, rv_w1, W1c_g, W1c_r,
      pe_w, peB,
      gti, te_w1, te_b1, te_w2, te_b2, ag_q_w, ag_q_b, ar_q_w, ar_q_b, q_g, q_r,
      gek_w2, gek_b2, ag_k_w, ag_k_b, Wk_g, bk_g,
      gev_w2, gev_b2, ag_v_w, ag_v_b, Wv_g, bv_g,
      rk_w2,  rk_b2,  ar_k_w, ar_k_b, Wk_r, bk_r,
      rv_w2,  rv_b2,  ar_v_w, ar_v_b, Wv_r, bv_r);
  k_wvopk<<<dim3(129, 16), 128, 0, stream>>>(
      Wv_g, bv_g, ag_o_w, ag_o_b, Wvo_g, bvo_g,
      Wv_r, bv_r, ar_o_w, ar_o_b, Wvo_r, bvo_r,
      Wk_g, bk_g, q_g, PkT_g, ck_g,
      Wk_r, bk_r, q_r, PkT_r, ck_r);

  // graph branch: 49152 keys/batch, 128 chunks x 384 keys (6 tiles of 64)
  k_flash<64, 1, false><<<dim3(128, 4), 256, 0, stream>>>(
      gf, (const float*)nullptr, 0, W1c_g, gek_b1, gev_b1, PkT_g, ck_g,
      accP_g, lP_g, 49152, 384);
  // grid branch: patch conv (split-K 8) -> bf16 partials
  k_patch<<<dim3(96, 8), 256, 0, stream>>>(gridf, peB, patchP);
  k_ogred<<<dim3(24, 4), 256, 0, stream>>>(accP_g, lP_g, 128, Wvo_g, bvo_g, og_g);
  k_flash<128, 8, true><<<dim3(24, 4), 256, 0, stream>>>(
      patchP, pe_b, 786432, W1c_r, rk_b1, rv_b1, PkT_r, ck_r,
      accP_r, lP_r, 1536, 64);
  k_ogred<<<dim3(24, 4), 256, 0, stream>>>(accP_r, lP_r, 24, Wvo_r, bvo_r, og_r);
  k_U<<<128, 256, 0, stream>>>(og_r, up_w, U);
  k_upall<<<8192, 256, 0, stream>>>(og_g, U, up_b, out, out + 25165824);
}

// Round 5
// 425.421 us; speedup vs baseline: 1.1360x; 1.1360x over previous
//
#include <hip/hip_runtime.h>

// ---------------------------------------------------------------------------
// GraphGridCrossAttnModel — round 5: r3 flash structure (Pk in LDS — the
// r4 Pk-in-VGPR variant spilled and regressed 376->483) + r4's keepers:
// bf16 intermediates (accP/patchP) and fused launches (9 dispatches).
// B=4 T=24 N=2048 DG=64 E=128 NH=4 HD=32 H=W=64 P=8 -> NP=64
// MFMA layout (16x16x32 bf16, m89-verified):
//  A: m=l&15, k=(l>>4)*8+j ; B: n=l&15, k=(l>>4)*8+j ; D: col=l&15, row=(l>>4)*4+reg
// ---------------------------------------------------------------------------

typedef unsigned short u16;
using bf8 = __attribute__((ext_vector_type(8))) short;
using f4v = __attribute__((ext_vector_type(4))) float;
#define MFMA16(a, b, c) __builtin_amdgcn_mfma_f32_16x16x32_bf16(a, b, c, 0, 0, 0)

constexpr float INV_SCALE = 0.17677669529663687f;   // 1/sqrt(32)

__device__ __forceinline__ u16 f2bf(float f) {
  unsigned u = __float_as_uint(f);
  u += 0x7FFFu + ((u >> 16) & 1u);
  return (u16)(u >> 16);
}
__device__ __forceinline__ unsigned pk2(float a, float b) {
  return (unsigned)f2bf(a) | ((unsigned)f2bf(b) << 16);
}
__device__ __forceinline__ float bflo(unsigned v) { return __uint_as_float(v << 16); }
__device__ __forceinline__ float bfhi(unsigned v) { return __uint_as_float(v & 0xffff0000u); }

// ---------------- fused precompute: w1c | cvt | teq | fold -------------------

__global__ __launch_bounds__(128) void k_pre1(
    const float* gk_w1, const float* gv_w1, const float* rk_w1, const float* rv_w1,
    u16* W1c_g, u16* W1c_r,
    const float* pe_w, u16* peB,
    const float* tidx, const float* te_w1, const float* te_b1,
    const float* te_w2, const float* te_b2,
    const float* wg, const float* bg, const float* wr, const float* br,
    float* qg, float* qr,
    const float* A0, const float* Ab0, const float* B0, const float* Bb0, float* O0, float* Ob0,
    const float* A1, const float* Ab1, const float* B1, const float* Bb1, float* O1, float* Ob1,
    const float* A2, const float* Ab2, const float* B2, const float* Bb2, float* O2, float* Ob2,
    const float* A3, const float* Ab3, const float* B3, const float* Bb3, float* O3, float* Ob3) {
  int x = blockIdx.x, e = threadIdx.x;
  __shared__ float sh[256];
  if (x < 512) {                    // --- W1c bf16 transpose-pack
    int c = x & 255, brn = x >> 8;
    int DIN = brn ? 128 : 64;
    if (e < DIN) {
      const float* src = brn ? (c < 128 ? rk_w1 : rv_w1) : (c < 128 ? gk_w1 : gv_w1);
      u16* dst = brn ? W1c_r : W1c_g;
      dst[c * DIN + e] = f2bf(src[e * 128 + (c & 127)]);
    }
  } else if (x < 1536) {            // --- pe_w -> bf16
    int i = ((x - 512) * 128 + e) * 8;
    float4 v0 = *(const float4*)(pe_w + i);
    float4 v1 = *(const float4*)(pe_w + i + 4);
    uint4 o; o.x = pk2(v0.x, v0.y); o.y = pk2(v0.z, v0.w);
    o.z = pk2(v1.x, v1.y); o.w = pk2(v1.z, v1.w);
    *(uint4*)&peB[i] = o;
  } else if (x < 1632) {            // --- te -> q_g/q_r
    int row = x - 1536;
    float tv = tidx[row];
    sh[e] = fmaxf(tv * te_w1[e] + te_b1[e], 0.f);
    __syncthreads();
    float a = te_b2[e];
    for (int j = 0; j < 128; ++j) a += sh[j] * te_w2[j * 128 + e];
    sh[128 + e] = a;
    __syncthreads();
    float ag = bg[e], ar = br[e];
    for (int j = 0; j < 128; ++j) {
      float xx = sh[128 + j];
      ag += xx * wg[j * 128 + e];
      ar += xx * wr[j * 128 + e];
    }
    qg[row * 128 + e] = ag;
    qr[row * 128 + e] = ar;
  } else {                          // --- fold W2@Wqkv
    int sub = x - 1632;
    int task = sub / 129, j = sub % 129;
    const float *A, *Ab, *Bm, *Bb; float *O, *Ob;
    switch (task) {
      case 0: A=A0; Ab=Ab0; Bm=B0; Bb=Bb0; O=O0; Ob=Ob0; break;
      case 1: A=A1; Ab=Ab1; Bm=B1; Bb=Bb1; O=O1; Ob=Ob1; break;
      case 2: A=A2; Ab=Ab2; Bm=B2; Bb=Bb2; O=O2; Ob=Ob2; break;
      default:A=A3; Ab=Ab3; Bm=B3; Bb=Bb3; O=O3; Ob=Ob3; break;
    }
    sh[e] = (j < 128) ? A[j * 128 + e] : Ab[e];
    __syncthreads();
    float acc = (j < 128) ? 0.f : Bb[e];
    for (int m = 0; m < 128; ++m) acc += sh[m] * Bm[m * 128 + e];
    if (j < 128) O[j * 128 + e] = acc; else Ob[e] = acc;
  }
}

// merged: y<8 -> Wvo/bvo tasks ; y>=8 -> PkT/ck tasks
__global__ __launch_bounds__(128) void k_wvopk(
    const float* Wv_g, const float* bv_g, const float* ow_g, const float* ob_g, float* Wvo_g, float* bvo_g,
    const float* Wv_r, const float* bv_r, const float* ow_r, const float* ob_r, float* Wvo_r, float* bvo_r,
    const float* Wk_g, const float* bk_g, const float* q_g, u16* PkT_g, float* ck_g,
    const float* Wk_r, const float* bk_r, const float* q_r, u16* PkT_r, float* ck_r) {
  int j = blockIdx.x, e = threadIdx.x;
  if (blockIdx.y < 8) {
    int br = blockIdx.y >> 2, h = blockIdx.y & 3;
    const float* Wv = br ? Wv_r : Wv_g;  const float* bv = br ? bv_r : bv_g;
    const float* ow = br ? ow_r : ow_g;  const float* ob = br ? ob_r : ob_g;
    float* Wvo = br ? Wvo_r : Wvo_g;     float* bvo = br ? bvo_r : bvo_g;
    if (j < 128) {
      __shared__ float wrow[32];
      if (e < 32) wrow[e] = Wv[j * 128 + h * 32 + e];
      __syncthreads();
      float acc = 0.f;
      for (int d = 0; d < 32; ++d) acc += wrow[d] * ow[(h * 32 + d) * 128 + e];
      Wvo[(h * 128 + j) * 128 + e] = acc;
    } else if (h == 0) {
      __shared__ float bbv[128];
      bbv[e] = bv[e];
      __syncthreads();
      float acc = ob[e];
      for (int m = 0; m < 128; ++m) acc += bbv[m] * ow[m * 128 + e];
      bvo[e] = acc;
    }
  } else {
    int y = blockIdx.y - 8;
    int br = y >> 2, b = y & 3;
    int hq = e;
    if (hq >= 96) return;
    const float* Wk = br ? Wk_r : Wk_g;  const float* bk = br ? bk_r : bk_g;
    const float* q  = br ? q_r  : q_g;
    u16* PkT = br ? PkT_r : PkT_g;       float* ck = br ? ck_r : ck_g;
    int h = hq / 24, t = hq % 24;
    const float* qrow = q + (b * 24 + t) * 128 + h * 32;
    if (j < 128) {
      const float* wrow = Wk + j * 128 + h * 32;
      float acc = 0.f;
      for (int d = 0; d < 32; ++d) acc += wrow[d] * qrow[d];
      PkT[((size_t)b * 96 + hq) * 136 + j] = f2bf(acc * INV_SCALE);
    } else {
      float acc = 0.f;
      for (int d = 0; d < 32; ++d) acc += bk[h * 32 + d] * qrow[d];
      ck[b * 96 + hq] = acc * INV_SCALE;
    }
  }
}

// ---------------- fused flash attention, bf16 MFMA ---------------------------
// 4 waves/block; 64-key tiles; Xt double-buffered; Pk staged in LDS (r3 form).

template <int DIN, int NRED, bool INBF>
__global__ __launch_bounds__(256, 2) void k_flash(
    const void* __restrict__ Xv, const float* __restrict__ redbias, size_t rstride,
    const u16* __restrict__ W1c,            // [256][DIN] bf16 (k cols | v cols)
    const float* __restrict__ b1k, const float* __restrict__ b1v,
    const u16* __restrict__ PkT,            // [b][96][136] bf16
    const float* __restrict__ ck,           // [b][96]
    u16* __restrict__ accP, float* __restrict__ lP,
    int KL, int kpb) {
  constexpr int KS = DIN / 32;
  constexpr int PD = DIN + 8;
  constexpr int PH = 136, PV = 72, PP = 72;
  constexpr int NR = DIN / 16;
  int b = blockIdx.y, chunk = blockIdx.x, nchunk = gridDim.x;
  int t = threadIdx.x;
  int l = t & 63, w = t >> 6;
  int l16 = l & 15, l4 = l >> 4;

  __shared__ __align__(16) u16 Xt[2][64 * PD];
  __shared__ __align__(16) u16 HB[9216];        // Hk[64][136] / HvT[128][72]
  __shared__ __align__(16) u16 Pt[96 * PP];
  __shared__ __align__(16) u16 Pk_s[96 * 136];
  __shared__ float lred[384];

  size_t xbase = (size_t)b * KL * DIN + (size_t)chunk * kpb * DIN;

  // stage PkT[b] into LDS (once per block)
  {
    const unsigned* ps = (const unsigned*)(PkT + (size_t)b * 96 * 136);
    unsigned* pd = (unsigned*)Pk_s;
    for (int i = t; i < 96 * 136 / 2; i += 256) pd[i] = ps[i];
  }

  bf8 wkA[2][KS], wvB[2][KS];
#pragma unroll
  for (int m = 0; m < 2; ++m)
#pragma unroll
    for (int ks = 0; ks < KS; ++ks) {
      int hid = w * 32 + m * 16 + l16;
      wkA[m][ks] = *(const bf8*)(W1c + (size_t)hid * DIN + ks * 32 + l4 * 8);
      wvB[m][ks] = *(const bf8*)(W1c + (size_t)(128 + hid) * DIN + ks * 32 + l4 * 8);
    }
  float bkA[2][4], bvB[2], ckr[6];
#pragma unroll
  for (int m = 0; m < 2; ++m)
#pragma unroll
    for (int r = 0; r < 4; ++r) bkA[m][r] = b1k[w * 32 + m * 16 + l4 * 4 + r];
#pragma unroll
  for (int n = 0; n < 2; ++n) bvB[n] = b1v[w * 32 + n * 16 + l16];
#pragma unroll
  for (int n = 0; n < 6; ++n) ckr[n] = ck[b * 96 + n * 16 + l16];

  f4v accO[6][2];
#pragma unroll
  for (int m = 0; m < 6; ++m)
#pragma unroll
    for (int n = 0; n < 2; ++n) accO[m][n] = (f4v){0.f, 0.f, 0.f, 0.f};
  float lacc[6] = {0.f, 0.f, 0.f, 0.f, 0.f, 0.f};

  float4 xr[NR];
  auto load_tile = [&](int kt) {
#pragma unroll
    for (int r = 0; r < NR; ++r) {
      int idx = (r * 256 + t) * 4;
      if constexpr (!INBF) {
        const float* Xrow = (const float*)Xv + xbase + (size_t)kt * 64 * DIN;
        xr[r] = *(const float4*)(Xrow + idx);
      } else {
        const u16* Xrow = (const u16*)Xv + xbase + (size_t)kt * 64 * DIN;
        int din = idx % DIN;
        float4 a = *(const float4*)(redbias + din);
#pragma unroll
        for (int c = 0; c < NRED; ++c) {
          uint2 v = *(const uint2*)(Xrow + (size_t)c * rstride + idx);
          a.x += bflo(v.x); a.y += bfhi(v.x);
          a.z += bflo(v.y); a.w += bfhi(v.y);
        }
        xr[r] = a;
      }
    }
  };

  int ntile = kpb >> 6;
  load_tile(0);
  int buf = 0;
  for (int kt = 0; kt < ntile; ++kt) {
    // ---- write staged tile (regs -> LDS bf16), prefetch next ----
#pragma unroll
    for (int r = 0; r < NR; ++r) {
      int idx = (r * 256 + t) * 4;
      int key = idx / DIN, din = idx % DIN;
      uint2 o; o.x = pk2(xr[r].x, xr[r].y); o.y = pk2(xr[r].z, xr[r].w);
      *(uint2*)&Xt[buf][key * PD + din] = o;
    }
    if (kt + 1 < ntile) load_tile(kt + 1);
    __syncthreads();                                   // b1

    // ---- G1a: Hk = W1k^T @ X^T ----
    {
      f4v hk[2][4];
#pragma unroll
      for (int m = 0; m < 2; ++m)
#pragma unroll
        for (int n = 0; n < 4; ++n) hk[m][n] = (f4v){0.f, 0.f, 0.f, 0.f};
#pragma unroll
      for (int ks = 0; ks < KS; ++ks) {
        bf8 xf[4];
#pragma unroll
        for (int n = 0; n < 4; ++n)
          xf[n] = *(const bf8*)&Xt[buf][(n * 16 + l16) * PD + ks * 32 + l4 * 8];
#pragma unroll
        for (int m = 0; m < 2; ++m)
#pragma unroll
          for (int n = 0; n < 4; ++n) hk[m][n] = MFMA16(wkA[m][ks], xf[n], hk[m][n]);
      }
#pragma unroll
      for (int m = 0; m < 2; ++m)
#pragma unroll
        for (int n = 0; n < 4; ++n) {
          int key = n * 16 + l16;
          int hid0 = w * 32 + m * 16 + l4 * 4;
          float v0 = fmaxf(hk[m][n][0] + bkA[m][0], 0.f);
          float v1 = fmaxf(hk[m][n][1] + bkA[m][1], 0.f);
          float v2 = fmaxf(hk[m][n][2] + bkA[m][2], 0.f);
          float v3 = fmaxf(hk[m][n][3] + bkA[m][3], 0.f);
          uint2 o; o.x = pk2(v0, v1); o.y = pk2(v2, v3);
          *(uint2*)&HB[key * PH + hid0] = o;
        }
    }
    __syncthreads();                                   // b2

    // ---- G2: S = Hk @ Pk ----
    {
      f4v sa[6];
#pragma unroll
      for (int n = 0; n < 6; ++n) sa[n] = (f4v){ckr[n], ckr[n], ckr[n], ckr[n]};
#pragma unroll
      for (int ks = 0; ks < 4; ++ks) {
        bf8 a = *(const bf8*)&HB[(w * 16 + l16) * PH + ks * 32 + l4 * 8];
#pragma unroll
        for (int n = 0; n < 6; ++n) {
          bf8 bp = *(const bf8*)&Pk_s[(n * 16 + l16) * 136 + ks * 32 + l4 * 8];
          sa[n] = MFMA16(a, bp, sa[n]);
        }
      }
#pragma unroll
      for (int n = 0; n < 6; ++n) {
        float e0 = __expf(sa[n][0]), e1 = __expf(sa[n][1]);
        float e2 = __expf(sa[n][2]), e3 = __expf(sa[n][3]);
        float ls = (e0 + e1) + (e2 + e3);
        ls += __shfl_xor(ls, 16);
        ls += __shfl_xor(ls, 32);
        lacc[n] += ls;
        uint2 o; o.x = pk2(e0, e1); o.y = pk2(e2, e3);
        *(uint2*)&Pt[(n * 16 + l16) * PP + w * 16 + l4 * 4] = o;
      }
    }
    __syncthreads();                                   // b3 (Hk dead, Pt ready)

    // ---- G1b: Hv = X @ W1v -> HvT[hid][key] ----
    {
      f4v hv[4][2];
#pragma unroll
      for (int m = 0; m < 4; ++m)
#pragma unroll
        for (int n = 0; n < 2; ++n) hv[m][n] = (f4v){0.f, 0.f, 0.f, 0.f};
#pragma unroll
      for (int ks = 0; ks < KS; ++ks) {
        bf8 xa[4];
#pragma unroll
        for (int m = 0; m < 4; ++m)
          xa[m] = *(const bf8*)&Xt[buf][(m * 16 + l16) * PD + ks * 32 + l4 * 8];
#pragma unroll
        for (int m = 0; m < 4; ++m)
#pragma unroll
          for (int n = 0; n < 2; ++n) hv[m][n] = MFMA16(xa[m], wvB[n][ks], hv[m][n]);
      }
#pragma unroll
      for (int m = 0; m < 4; ++m)
#pragma unroll
        for (int n = 0; n < 2; ++n) {
          int d = w * 32 + n * 16 + l16;
          int key0 = m * 16 + l4 * 4;
          float v0 = fmaxf(hv[m][n][0] + bvB[n], 0.f);
          float v1 = fmaxf(hv[m][n][1] + bvB[n], 0.f);
          float v2 = fmaxf(hv[m][n][2] + bvB[n], 0.f);
          float v3 = fmaxf(hv[m][n][3] + bvB[n], 0.f);
          uint2 o; o.x = pk2(v0, v1); o.y = pk2(v2, v3);
          *(uint2*)&HB[d * PV + key0] = o;
        }
    }
    __syncthreads();                                   // b4 (HvT ready)

    // ---- G3: ACC += P^T @ Hv ----
#pragma unroll
    for (int ks = 0; ks < 2; ++ks) {
      bf8 pa[6];
#pragma unroll
      for (int m = 0; m < 6; ++m)
        pa[m] = *(const bf8*)&Pt[(m * 16 + l16) * PP + ks * 32 + l4 * 8];
#pragma unroll
      for (int n = 0; n < 2; ++n) {
        bf8 hb = *(const bf8*)&HB[(w * 32 + n * 16 + l16) * PV + ks * 32 + l4 * 8];
#pragma unroll
        for (int m = 0; m < 6; ++m) accO[m][n] = MFMA16(pa[m], hb, accO[m][n]);
      }
    }
    buf ^= 1;
    // no trailing barrier: next write targets the other Xt buffer; b1 orders HB/Pt.
  }

  // ---- write partial ACC (96x128 bf16) and partial l (96 fp32) ----
  u16* ap = accP + (size_t)(b * nchunk + chunk) * 96 * 128;
#pragma unroll
  for (int m = 0; m < 6; ++m)
#pragma unroll
    for (int n = 0; n < 2; ++n) {
      int d = w * 32 + n * 16 + l16;
#pragma unroll
      for (int r = 0; r < 4; ++r) {
        int hq = m * 16 + l4 * 4 + r;
        ap[hq * 128 + d] = f2bf(accO[m][n][r]);
      }
    }
  if (l4 == 0) {
#pragma unroll
    for (int n = 0; n < 6; ++n) lred[w * 96 + n * 16 + l16] = lacc[n];
  }
  __syncthreads();
  if (t < 96) {
    float s = lred[t] + lred[96 + t] + lred[192 + t] + lred[288 + t];
    lP[(size_t)(b * nchunk + chunk) * 96 + t] = s;
  }
}

// ---------------- patch conv, bf16 MFMA (split-K 8, swizzled Wt) -------------

__global__ __launch_bounds__(256, 3) void k_patch(const float* __restrict__ X,
    const u16* __restrict__ peB, u16* __restrict__ patchP) {
  int bt = blockIdx.x, kc = blockIdx.y;
  int t = threadIdx.x;
  int l = t & 63, w = t >> 6;
  int l16 = l & 15, l4 = l >> 4;
  const float* Xbt = X + (size_t)bt * 524288 + (size_t)kc * 65536;

  __shared__ __align__(16) u16 Xp[64 * 136];
  __shared__ __align__(16) u16 Wt[128 * 128];   // XOR-swizzled: slot ^= co&7

  f4v acc[4][2];
#pragma unroll
  for (int m = 0; m < 4; ++m)
#pragma unroll
    for (int n = 0; n < 2; ++n) acc[m][n] = (f4v){0.f, 0.f, 0.f, 0.f};

  float4 xr[8];
  auto loadX = [&](int s) {
    const float* img = Xbt + (size_t)s * 8192;
#pragma unroll
    for (int r = 0; r < 8; ++r) xr[r] = *(const float4*)(img + (r * 256 + t) * 4);
  };
  loadX(0);

  for (int s = 0; s < 8; ++s) {
#pragma unroll
    for (int r = 0; r < 8; ++r) {
      int idx = (r * 256 + t) * 4;
      int cl = idx >> 12, off = idx & 4095;
      int h = off >> 6, w0 = off & 63;
      int patch = (h >> 3) * 8 + (w0 >> 3);
      int within = (h & 7) * 8 + (w0 & 7);
      uint2 o; o.x = pk2(xr[r].x, xr[r].y); o.y = pk2(xr[r].z, xr[r].w);
      *(uint2*)&Xp[patch * 136 + cl * 64 + within] = o;
    }
    {
      int colbase = kc * 1024 + s * 128;
#pragma unroll
      for (int r = 0; r < 8; ++r) {
        int idx = r * 256 + t;
        int co = idx >> 4, part = idx & 15;
        int slot = part ^ (co & 7);
        uint4 v = *(const uint4*)(peB + (size_t)co * 8192 + colbase + part * 8);
        *(uint4*)&Wt[co * 128 + slot * 8] = v;
      }
    }
    if (s < 7) loadX(s + 1);
    __syncthreads();
#pragma unroll
    for (int ks2 = 0; ks2 < 4; ++ks2) {
      bf8 af[4];
#pragma unroll
      for (int m = 0; m < 4; ++m)
        af[m] = *(const bf8*)&Xp[(m * 16 + l16) * 136 + ks2 * 32 + l4 * 8];
#pragma unroll
      for (int n = 0; n < 2; ++n) {
        int co = w * 32 + n * 16 + l16;
        int slot = (ks2 * 4 + l4) ^ (co & 7);
        bf8 bf_ = *(const bf8*)&Wt[co * 128 + slot * 8];
#pragma unroll
        for (int m = 0; m < 4; ++m) acc[m][n] = MFMA16(af[m], bf_, acc[m][n]);
      }
    }
    __syncthreads();
  }
  u16* outp = patchP + ((size_t)kc * 6144 + bt * 64) * 128;
#pragma unroll
  for (int m = 0; m < 4; ++m)
#pragma unroll
    for (int n = 0; n < 2; ++n) {
      int d = w * 32 + n * 16 + l16;
#pragma unroll
      for (int r = 0; r < 4; ++r) {
        int patch = m * 16 + l4 * 4 + r;
        outp[patch * 128 + d] = f2bf(acc[m][n][r]);
      }
    }
}

// ---------------- merged chunk-reduce + og ----------------------------------

__global__ __launch_bounds__(256) void k_ogred(const u16* __restrict__ accP,
    const float* __restrict__ lP, int nchunk,
    const float* __restrict__ Wvo, const float* __restrict__ bvo,
    float* __restrict__ og) {
  int t = blockIdx.x, b = blockIdx.y, tid = threadIdx.x;
  __shared__ float op[512];
  __shared__ float invl[4];
  for (int p = tid; p < 512; p += 256) {
    int h = p >> 7, e = p & 127;
    const u16* src = accP + ((size_t)b * nchunk * 96 + h * 24 + t) * 128 + e;
    float s = 0.f;
    for (int c = 0; c < nchunk; ++c) s += bflo((unsigned)src[(size_t)c * 12288]);
    op[p] = s;
  }
  if (tid < 4) {
    const float* lp = lP + (size_t)b * nchunk * 96 + tid * 24 + t;
    float ls = 0.f;
    for (int c = 0; c < nchunk; ++c) ls += lp[(size_t)c * 96];
    invl[tid] = 1.f / ls;
  }
  __syncthreads();
  for (int p = tid; p < 512; p += 256) op[p] *= invl[p >> 7];
  __syncthreads();
  if (tid < 128) {
    int e = tid;
    float acc = bvo[e];
    for (int h = 0; h < 4; ++h)
      for (int j = 0; j < 128; ++j) acc += op[h * 128 + j] * Wvo[(h * 128 + j) * 128 + e];
    og[(b * 24 + t) * 128 + e] = acc;
  }
}

// U = og_r @ up_w : block owns 64 out-cols, og (48KB) in LDS, up_w read ONCE.
__global__ __launch_bounds__(256) void k_U(const float* __restrict__ og_r,
    const float* __restrict__ up_w, float* __restrict__ U) {
  int col = blockIdx.x * 64 + (threadIdx.x & 63);
  int rg = threadIdx.x >> 6;               // 4 row-groups x 24 rows
  __shared__ float og_s[96 * 128];
  for (int i = threadIdx.x; i < 96 * 128 / 4; i += 256)
    ((float4*)og_s)[i] = ((const float4*)og_r)[i];
  __syncthreads();
  float acc[24];
#pragma unroll
  for (int r = 0; r < 24; ++r) acc[r] = 0.f;
#pragma unroll 4
  for (int c = 0; c < 128; ++c) {
    float wv = up_w[(size_t)c * 8192 + col];
#pragma unroll
    for (int r = 0; r < 24; ++r) acc[r] += og_s[(rg * 24 + r) * 128 + c] * wv;
  }
#pragma unroll
  for (int r = 0; r < 24; ++r) U[(size_t)(rg * 24 + r) * 8192 + col] = acc[r];
}

// ---------------- merged output writer: gout | up ----------------------------

__global__ __launch_bounds__(256) void k_upall(const float* __restrict__ og,
    const float* __restrict__ U, const float* __restrict__ up_b,
    float* __restrict__ outg, float* __restrict__ outu) {
  int x = blockIdx.x;
  if (x < 4096) {                       // ---- g_out lerp writer
    int b = x >> 10;
    const float* ogb = og + b * 3072;
    float* ob = outg + (size_t)b * 6291456;
    for (int i4 = (x & 1023) * 256 + threadIdx.x; i4 < 1572864; i4 += 1024 * 256) {
      int i = i4 * 4;
      int n = i >> 7, e = i & 127;
      float src = fmaxf((n + 0.5f) * (1.f / 2048.f) - 0.5f, 0.f);
      int t0 = (int)src; float lam = src - (float)t0; int t1 = min(t0 + 1, 23);
      float4 a = *(const float4*)&ogb[t0 * 128 + e];
      float4 c = *(const float4*)&ogb[t1 * 128 + e];
      float4 o;
      o.x = a.x + lam * (c.x - a.x); o.y = a.y + lam * (c.y - a.y);
      o.z = a.z + lam * (c.z - a.z); o.w = a.w + lam * (c.w - a.w);
      *(float4*)&ob[i] = o;
    }
  } else {                              // ---- up lerp-upsample writer
    for (int i4 = (x - 4096) * 256 + threadIdx.x; i4 < 12582912; i4 += 4096 * 256) {
      int i = i4 * 4;
      int w0 = i & 63;
      int h  = (i >> 6) & 63;
      int o  = (i >> 12) & 127;
      int bt = i >> 19;                 // 0..95
      int b = bt / 24, tt = bt - b * 24;
      int ii = h >> 3, p = h & 7, j = w0 >> 3, q0 = w0 & 7;
      int n = tt * 64 + ii * 8 + j;
      float src = fmaxf((n + 0.5f) * (1.f / 64.f) - 0.5f, 0.f);
      int t0 = (int)src; float lam = src - (float)t0; int t1 = min(t0 + 1, 23);
      const float* u0 = U + (size_t)(b * 24 + t0) * 8192 + o * 64 + p * 8 + q0;
      const float* u1 = U + (size_t)(b * 24 + t1) * 8192 + o * 64 + p * 8 + q0;
      float bb = up_b[o];
      float4 a = *(const float4*)u0, c = *(const float4*)u1;
      float4 r;
      r.x = a.x + lam * (c.x - a.x) + bb; r.y = a.y + lam * (c.y - a.y) + bb;
      r.z = a.z + lam * (c.z - a.z) + bb; r.w = a.w + lam * (c.w - a.w) + bb;
      *(float4*)&outu[i] = r;
    }
  }
}

// ---------------------------------------------------------------------------

extern "C" void kernel_launch(void* const* d_in, const int* in_sizes, int n_in,
                              void* d_out, int out_size, void* d_ws, size_t ws_size,
                              hipStream_t stream) {
  (void)in_sizes; (void)n_in; (void)out_size; (void)ws_size;
  const float* gf    = (const float*)d_in[0];
  const float* gridf = (const float*)d_in[1];
  const float* gti   = (const float*)d_in[2];
  const float* gek_w1 = (const float*)d_in[4],  *gek_b1 = (const float*)d_in[5];
  const float* gek_w2 = (const float*)d_in[6],  *gek_b2 = (const float*)d_in[7];
  const float* gev_w1 = (const float*)d_in[8],  *gev_b1 = (const float*)d_in[9];
  const float* gev_w2 = (const float*)d_in[10], *gev_b2 = (const float*)d_in[11];
  const float* rk_w1  = (const float*)d_in[12], *rk_b1  = (const float*)d_in[13];
  const float* rk_w2  = (const float*)d_in[14], *rk_b2  = (const float*)d_in[15];
  const float* rv_w1  = (const float*)d_in[16], *rv_b1  = (const float*)d_in[17];
  const float* rv_w2  = (const float*)d_in[18], *rv_b2  = (const float*)d_in[19];
  const float* te_w1  = (const float*)d_in[20], *te_b1  = (const float*)d_in[21];
  const float* te_w2  = (const float*)d_in[22], *te_b2  = (const float*)d_in[23];
  const float* pe_w   = (const float*)d_in[24], *pe_b   = (const float*)d_in[25];
  const float* up_w   = (const float*)d_in[26], *up_b   = (const float*)d_in[27];
  const float* ag_q_w = (const float*)d_in[28], *ag_q_b = (const float*)d_in[29];
  const float* ag_k_w = (const float*)d_in[30], *ag_k_b = (const float*)d_in[31];
  const float* ag_v_w = (const float*)d_in[32], *ag_v_b = (const float*)d_in[33];
  const float* ag_o_w = (const float*)d_in[34], *ag_o_b = (const float*)d_in[35];
  const float* ar_q_w = (const float*)d_in[36], *ar_q_b = (const float*)d_in[37];
  const float* ar_k_w = (const float*)d_in[38], *ar_k_b = (const float*)d_in[39];
  const float* ar_v_w = (const float*)d_in[40], *ar_v_b = (const float*)d_in[41];
  const float* ar_o_w = (const float*)d_in[42], *ar_o_b = (const float*)d_in[43];

  float* out = (float*)d_out;          // g_out (25165824 f) then up (50331648 f)
  float* ws = (float*)d_ws;
  size_t off = 0;
  auto A = [&](size_t n) { float* p = ws + off; off += n; return p; };
  float* q_g   = A(12288);   float* q_r   = A(12288);
  float* Wk_g  = A(16384);   float* bk_g  = A(128);
  float* Wv_g  = A(16384);   float* bv_g  = A(128);
  float* Wk_r  = A(16384);   float* bk_r  = A(128);
  float* Wv_r  = A(16384);   float* bv_r  = A(128);
  float* Wvo_g = A(65536);   float* bvo_g = A(128);
  float* Wvo_r = A(65536);   float* bvo_r = A(128);
  float* ck_g  = A(384);     float* ck_r  = A(384);
  u16*   PkT_g = (u16*)A(26112);   // 4*96*136 bf16
  u16*   PkT_r = (u16*)A(26112);
  u16*   W1c_g = (u16*)A(8192);    // 256*64 bf16
  u16*   W1c_r = (u16*)A(16384);   // 256*128 bf16
  u16*   peB   = (u16*)A(524288);  // 128*8192 bf16
  float* lP_g  = A(49152);   float* lP_r  = A(9216);
  float* og_g  = A(12288);   float* og_r  = A(12288);
  u16*   accP_g = (u16*)A(3145728);   // 4*128*12288 bf16
  u16*   patchP = (u16*)A(3145728);   // 8*6144*128 bf16
  u16*   accP_r = (u16*)A(589824);    // 4*24*12288 bf16
  float* U      = A(786432);
  // total ~8.6M floats (~34 MB)

  k_pre1<<<2148, 128, 0, stream>>>(
      gek_w1, gev_w1, rk_w1, rv_w1, W1c_g, W1c_r,
      pe_w, peB,
      gti, te_w1, te_b1, te_w2, te_b2, ag_q_w, ag_q_b, ar_q_w, ar_q_b, q_g, q_r,
      gek_w2, gek_b2, ag_k_w, ag_k_b, Wk_g, bk_g,
      gev_w2, gev_b2, ag_v_w, ag_v_b, Wv_g, bv_g,
      rk_w2,  rk_b2,  ar_k_w, ar_k_b, Wk_r, bk_r,
      rv_w2,  rv_b2,  ar_v_w, ar_v_b, Wv_r, bv_r);
  k_wvopk<<<dim3(129, 16), 128, 0, stream>>>(
      Wv_g, bv_g, ag_o_w, ag_o_b, Wvo_g, bvo_g,
      Wv_r, bv_r, ar_o_w, ar_o_b, Wvo_r, bvo_r,
      Wk_g, bk_g, q_g, PkT_g, ck_g,
      Wk_r, bk_r, q_r, PkT_r, ck_r);

  // graph branch: 49152 keys/batch, 128 chunks x 384 keys (6 tiles of 64)
  k_flash<64, 1, false><<<dim3(128, 4), 256, 0, stream>>>(
      gf, (const float*)nullptr, 0, W1c_g, gek_b1, gev_b1, PkT_g, ck_g,
      accP_g, lP_g, 49152, 384);
  // grid branch: patch conv (split-K 8) -> bf16 partials
  k_patch<<<dim3(96, 8), 256, 0, stream>>>(gridf, peB, patchP);
  k_ogred<<<dim3(24, 4), 256, 0, stream>>>(accP_g, lP_g, 128, Wvo_g, bvo_g, og_g);
  k_flash<128, 8, true><<<dim3(24, 4), 256, 0, stream>>>(
      patchP, pe_b, 786432, W1c_r, rk_b1, rv_b1, PkT_r, ck_r,
      accP_r, lP_r, 1536, 64);
  k_ogred<<<dim3(24, 4), 256, 0, stream>>>(accP_r, lP_r, 24, Wvo_r, bvo_r, og_r);
  k_U<<<128, 256, 0, stream>>>(og_r, up_w, U);
  k_upall<<<8192, 256, 0, stream>>>(og_g, U, up_b, out, out + 25165824);
}

// Round 6
// 236.219 us; speedup vs baseline: 2.0459x; 1.8010x over previous
//
#include <hip/hip_runtime.h>

// ---------------------------------------------------------------------------
// GraphGridCrossAttnModel — round 6: dispatch-count attack. 6 dispatches:
//   K1 pre1 | K2 wvopk | K3 {flash64 || patch} | K4 {ogred_g || flash128}
//   K5 {ogred_r || gout} | K6 upfuse (k_U + up-writer fused)
// flash: 3 barriers/tile (b4 dropped: G3 reads only own-wave HvT rows; DS ops
// are in-order per wave). Everything else identical to r5 (425us) internals.
// MFMA layout (16x16x32 bf16, m89-verified):
//  A: m=l&15, k=(l>>4)*8+j ; B: n=l&15, k=(l>>4)*8+j ; D: col=l&15, row=(l>>4)*4+reg
// ---------------------------------------------------------------------------

typedef unsigned short u16;
using bf8 = __attribute__((ext_vector_type(8))) short;
using f4v = __attribute__((ext_vector_type(4))) float;
#define MFMA16(a, b, c) __builtin_amdgcn_mfma_f32_16x16x32_bf16(a, b, c, 0, 0, 0)

constexpr float INV_SCALE = 0.17677669529663687f;   // 1/sqrt(32)

__device__ __forceinline__ u16 f2bf(float f) {
  unsigned u = __float_as_uint(f);
  u += 0x7FFFu + ((u >> 16) & 1u);
  return (u16)(u >> 16);
}
__device__ __forceinline__ unsigned pk2(float a, float b) {
  return (unsigned)f2bf(a) | ((unsigned)f2bf(b) << 16);
}
__device__ __forceinline__ float bflo(unsigned v) { return __uint_as_float(v << 16); }
__device__ __forceinline__ float bfhi(unsigned v) { return __uint_as_float(v & 0xffff0000u); }

// ---------------- K1: fused precompute: w1c | cvt | teq | fold ---------------

__global__ __launch_bounds__(128) void k_pre1(
    const float* gk_w1, const float* gv_w1, const float* rk_w1, const float* rv_w1,
    u16* W1c_g, u16* W1c_r,
    const float* pe_w, u16* peB,
    const float* tidx, const float* te_w1, const float* te_b1,
    const float* te_w2, const float* te_b2,
    const float* wg, const float* bg, const float* wr, const float* br,
    float* qg, float* qr,
    const float* A0, const float* Ab0, const float* B0, const float* Bb0, float* O0, float* Ob0,
    const float* A1, const float* Ab1, const float* B1, const float* Bb1, float* O1, float* Ob1,
    const float* A2, const float* Ab2, const float* B2, const float* Bb2, float* O2, float* Ob2,
    const float* A3, const float* Ab3, const float* B3, const float* Bb3, float* O3, float* Ob3) {
  int x = blockIdx.x, e = threadIdx.x;
  __shared__ float sh[256];
  if (x < 512) {                    // --- W1c bf16 transpose-pack
    int c = x & 255, brn = x >> 8;
    int DIN = brn ? 128 : 64;
    if (e < DIN) {
      const float* src = brn ? (c < 128 ? rk_w1 : rv_w1) : (c < 128 ? gk_w1 : gv_w1);
      u16* dst = brn ? W1c_r : W1c_g;
      dst[c * DIN + e] = f2bf(src[e * 128 + (c & 127)]);
    }
  } else if (x < 1536) {            // --- pe_w -> bf16
    int i = ((x - 512) * 128 + e) * 8;
    float4 v0 = *(const float4*)(pe_w + i);
    float4 v1 = *(const float4*)(pe_w + i + 4);
    uint4 o; o.x = pk2(v0.x, v0.y); o.y = pk2(v0.z, v0.w);
    o.z = pk2(v1.x, v1.y); o.w = pk2(v1.z, v1.w);
    *(uint4*)&peB[i] = o;
  } else if (x < 1632) {            // --- te -> q_g/q_r
    int row = x - 1536;
    float tv = tidx[row];
    sh[e] = fmaxf(tv * te_w1[e] + te_b1[e], 0.f);
    __syncthreads();
    float a = te_b2[e];
    for (int j = 0; j < 128; ++j) a += sh[j] * te_w2[j * 128 + e];
    sh[128 + e] = a;
    __syncthreads();
    float ag = bg[e], ar = br[e];
    for (int j = 0; j < 128; ++j) {
      float xx = sh[128 + j];
      ag += xx * wg[j * 128 + e];
      ar += xx * wr[j * 128 + e];
    }
    qg[row * 128 + e] = ag;
    qr[row * 128 + e] = ar;
  } else {                          // --- fold W2@Wqkv
    int sub = x - 1632;
    int task = sub / 129, j = sub % 129;
    const float *A, *Ab, *Bm, *Bb; float *O, *Ob;
    switch (task) {
      case 0: A=A0; Ab=Ab0; Bm=B0; Bb=Bb0; O=O0; Ob=Ob0; break;
      case 1: A=A1; Ab=Ab1; Bm=B1; Bb=Bb1; O=O1; Ob=Ob1; break;
      case 2: A=A2; Ab=Ab2; Bm=B2; Bb=Bb2; O=O2; Ob=Ob2; break;
      default:A=A3; Ab=Ab3; Bm=B3; Bb=Bb3; O=O3; Ob=Ob3; break;
    }
    sh[e] = (j < 128) ? A[j * 128 + e] : Ab[e];
    __syncthreads();
    float acc = (j < 128) ? 0.f : Bb[e];
    for (int m = 0; m < 128; ++m) acc += sh[m] * Bm[m * 128 + e];
    if (j < 128) O[j * 128 + e] = acc; else Ob[e] = acc;
  }
}

// ---------------- K2: merged Wvo/bvo + PkT/ck --------------------------------

__global__ __launch_bounds__(128) void k_wvopk(
    const float* Wv_g, const float* bv_g, const float* ow_g, const float* ob_g, float* Wvo_g, float* bvo_g,
    const float* Wv_r, const float* bv_r, const float* ow_r, const float* ob_r, float* Wvo_r, float* bvo_r,
    const float* Wk_g, const float* bk_g, const float* q_g, u16* PkT_g, float* ck_g,
    const float* Wk_r, const float* bk_r, const float* q_r, u16* PkT_r, float* ck_r) {
  int j = blockIdx.x, e = threadIdx.x;
  if (blockIdx.y < 8) {
    int br = blockIdx.y >> 2, h = blockIdx.y & 3;
    const float* Wv = br ? Wv_r : Wv_g;  const float* bv = br ? bv_r : bv_g;
    const float* ow = br ? ow_r : ow_g;  const float* ob = br ? ob_r : ob_g;
    float* Wvo = br ? Wvo_r : Wvo_g;     float* bvo = br ? bvo_r : bvo_g;
    if (j < 128) {
      __shared__ float wrow[32];
      if (e < 32) wrow[e] = Wv[j * 128 + h * 32 + e];
      __syncthreads();
      float acc = 0.f;
      for (int d = 0; d < 32; ++d) acc += wrow[d] * ow[(h * 32 + d) * 128 + e];
      Wvo[(h * 128 + j) * 128 + e] = acc;
    } else if (h == 0) {
      __shared__ float bbv[128];
      bbv[e] = bv[e];
      __syncthreads();
      float acc = ob[e];
      for (int m = 0; m < 128; ++m) acc += bbv[m] * ow[m * 128 + e];
      bvo[e] = acc;
    }
  } else {
    int y = blockIdx.y - 8;
    int br = y >> 2, b = y & 3;
    int hq = e;
    if (hq >= 96) return;
    const float* Wk = br ? Wk_r : Wk_g;  const float* bk = br ? bk_r : bk_g;
    const float* q  = br ? q_r  : q_g;
    u16* PkT = br ? PkT_r : PkT_g;       float* ck = br ? ck_r : ck_g;
    int h = hq / 24, t = hq % 24;
    const float* qrow = q + (b * 24 + t) * 128 + h * 32;
    if (j < 128) {
      const float* wrow = Wk + j * 128 + h * 32;
      float acc = 0.f;
      for (int d = 0; d < 32; ++d) acc += wrow[d] * qrow[d];
      PkT[((size_t)b * 96 + hq) * 136 + j] = f2bf(acc * INV_SCALE);
    } else {
      float acc = 0.f;
      for (int d = 0; d < 32; ++d) acc += bk[h * 32 + d] * qrow[d];
      ck[b * 96 + hq] = acc * INV_SCALE;
    }
  }
}

// ---------------- flash body (device fn, LDS carved from smem) ---------------
// 4 waves; 64-key tiles; Xt double-buffered; 3 barriers/tile.

template <int DIN, int NRED, bool INBF>
__device__ __forceinline__ void flash_body(char* smem,
    const void* __restrict__ Xv, const float* __restrict__ redbias, size_t rstride,
    const u16* __restrict__ W1c, const float* __restrict__ b1k, const float* __restrict__ b1v,
    const u16* __restrict__ PkT, const float* __restrict__ ck,
    u16* __restrict__ accP, float* __restrict__ lP,
    int KL, int kpb, int chunk, int b, int nchunk) {
  constexpr int KS = DIN / 32;
  constexpr int PD = DIN + 8;
  constexpr int PH = 136, PV = 72, PP = 72;
  constexpr int NR = DIN / 16;
  constexpr int XTN = 64 * PD;                  // u16 per Xt buffer
  u16* Xt   = (u16*)smem;                       // [2][XTN]
  u16* HB   = (u16*)(smem + 4 * XTN);           // 9216 u16
  u16* Pt   = (u16*)(smem + 4 * XTN + 18432);   // 96*72
  u16* Pk_s = (u16*)(smem + 4 * XTN + 18432 + 13824);   // 96*136
  float* lred = (float*)(smem + 4 * XTN + 18432 + 13824 + 26112);  // 384 f

  int t = threadIdx.x;
  int l = t & 63, w = t >> 6;
  int l16 = l & 15, l4 = l >> 4;

  size_t xbase = (size_t)b * KL * DIN + (size_t)chunk * kpb * DIN;

  // stage PkT[b] into LDS (once per block)
  {
    const unsigned* ps = (const unsigned*)(PkT + (size_t)b * 96 * 136);
    unsigned* pd = (unsigned*)Pk_s;
    for (int i = t; i < 96 * 136 / 2; i += 256) pd[i] = ps[i];
  }

  bf8 wkA[2][KS], wvB[2][KS];
#pragma unroll
  for (int m = 0; m < 2; ++m)
#pragma unroll
    for (int ks = 0; ks < KS; ++ks) {
      int hid = w * 32 + m * 16 + l16;
      wkA[m][ks] = *(const bf8*)(W1c + (size_t)hid * DIN + ks * 32 + l4 * 8);
      wvB[m][ks] = *(const bf8*)(W1c + (size_t)(128 + hid) * DIN + ks * 32 + l4 * 8);
    }
  float bkA[2][4], bvB[2], ckr[6];
#pragma unroll
  for (int m = 0; m < 2; ++m)
#pragma unroll
    for (int r = 0; r < 4; ++r) bkA[m][r] = b1k[w * 32 + m * 16 + l4 * 4 + r];
#pragma unroll
  for (int n = 0; n < 2; ++n) bvB[n] = b1v[w * 32 + n * 16 + l16];
#pragma unroll
  for (int n = 0; n < 6; ++n) ckr[n] = ck[b * 96 + n * 16 + l16];

  f4v accO[6][2];
#pragma unroll
  for (int m = 0; m < 6; ++m)
#pragma unroll
    for (int n = 0; n < 2; ++n) accO[m][n] = (f4v){0.f, 0.f, 0.f, 0.f};
  float lacc[6] = {0.f, 0.f, 0.f, 0.f, 0.f, 0.f};

  float4 xr[NR];
  auto load_tile = [&](int kt) {
#pragma unroll
    for (int r = 0; r < NR; ++r) {
      int idx = (r * 256 + t) * 4;
      if constexpr (!INBF) {
        const float* Xrow = (const float*)Xv + xbase + (size_t)kt * 64 * DIN;
        xr[r] = *(const float4*)(Xrow + idx);
      } else {
        const u16* Xrow = (const u16*)Xv + xbase + (size_t)kt * 64 * DIN;
        int din = idx % DIN;
        float4 a = *(const float4*)(redbias + din);
#pragma unroll
        for (int c = 0; c < NRED; ++c) {
          uint2 v = *(const uint2*)(Xrow + (size_t)c * rstride + idx);
          a.x += bflo(v.x); a.y += bfhi(v.x);
          a.z += bflo(v.y); a.w += bfhi(v.y);
        }
        xr[r] = a;
      }
    }
  };

  int ntile = kpb >> 6;
  load_tile(0);
  int buf = 0;
  for (int kt = 0; kt < ntile; ++kt) {
    // ---- write staged tile (regs -> LDS bf16), prefetch next ----
#pragma unroll
    for (int r = 0; r < NR; ++r) {
      int idx = (r * 256 + t) * 4;
      int key = idx / DIN, din = idx % DIN;
      uint2 o; o.x = pk2(xr[r].x, xr[r].y); o.y = pk2(xr[r].z, xr[r].w);
      *(uint2*)&Xt[buf * XTN + key * PD + din] = o;
    }
    if (kt + 1 < ntile) load_tile(kt + 1);
    __syncthreads();                                   // b1 (Xt ready; HB free)

    // ---- G1a: Hk = W1k^T @ X^T ----
    {
      f4v hk[2][4];
#pragma unroll
      for (int m = 0; m < 2; ++m)
#pragma unroll
        for (int n = 0; n < 4; ++n) hk[m][n] = (f4v){0.f, 0.f, 0.f, 0.f};
#pragma unroll
      for (int ks = 0; ks < KS; ++ks) {
        bf8 xf[4];
#pragma unroll
        for (int n = 0; n < 4; ++n)
          xf[n] = *(const bf8*)&Xt[buf * XTN + (n * 16 + l16) * PD + ks * 32 + l4 * 8];
#pragma unroll
        for (int m = 0; m < 2; ++m)
#pragma unroll
          for (int n = 0; n < 4; ++n) hk[m][n] = MFMA16(wkA[m][ks], xf[n], hk[m][n]);
      }
#pragma unroll
      for (int m = 0; m < 2; ++m)
#pragma unroll
        for (int n = 0; n < 4; ++n) {
          int key = n * 16 + l16;
          int hid0 = w * 32 + m * 16 + l4 * 4;
          float v0 = fmaxf(hk[m][n][0] + bkA[m][0], 0.f);
          float v1 = fmaxf(hk[m][n][1] + bkA[m][1], 0.f);
          float v2 = fmaxf(hk[m][n][2] + bkA[m][2], 0.f);
          float v3 = fmaxf(hk[m][n][3] + bkA[m][3], 0.f);
          uint2 o; o.x = pk2(v0, v1); o.y = pk2(v2, v3);
          *(uint2*)&HB[key * PH + hid0] = o;
        }
    }
    __syncthreads();                                   // b2 (Hk ready)

    // ---- G2: S = Hk @ Pk ----
    {
      f4v sa[6];
#pragma unroll
      for (int n = 0; n < 6; ++n) sa[n] = (f4v){ckr[n], ckr[n], ckr[n], ckr[n]};
#pragma unroll
      for (int ks = 0; ks < 4; ++ks) {
        bf8 a = *(const bf8*)&HB[(w * 16 + l16) * PH + ks * 32 + l4 * 8];
#pragma unroll
        for (int n = 0; n < 6; ++n) {
          bf8 bp = *(const bf8*)&Pk_s[(n * 16 + l16) * 136 + ks * 32 + l4 * 8];
          sa[n] = MFMA16(a, bp, sa[n]);
        }
      }
#pragma unroll
      for (int n = 0; n < 6; ++n) {
        float e0 = __expf(sa[n][0]), e1 = __expf(sa[n][1]);
        float e2 = __expf(sa[n][2]), e3 = __expf(sa[n][3]);
        float ls = (e0 + e1) + (e2 + e3);
        ls += __shfl_xor(ls, 16);
        ls += __shfl_xor(ls, 32);
        lacc[n] += ls;
        uint2 o; o.x = pk2(e0, e1); o.y = pk2(e2, e3);
        *(uint2*)&Pt[(n * 16 + l16) * PP + w * 16 + l4 * 4] = o;
      }
    }
    __syncthreads();                                   // b3 (Pt ready; HB-k readers done)

    // ---- G1b: Hv = X @ W1v -> HvT[hid][key] (own-wave rows) ----
    {
      f4v hv[4][2];
#pragma unroll
      for (int m = 0; m < 4; ++m)
#pragma unroll
        for (int n = 0; n < 2; ++n) hv[m][n] = (f4v){0.f, 0.f, 0.f, 0.f};
#pragma unroll
      for (int ks = 0; ks < KS; ++ks) {
        bf8 xa[4];
#pragma unroll
        for (int m = 0; m < 4; ++m)
          xa[m] = *(const bf8*)&Xt[buf * XTN + (m * 16 + l16) * PD + ks * 32 + l4 * 8];
#pragma unroll
        for (int m = 0; m < 4; ++m)
#pragma unroll
          for (int n = 0; n < 2; ++n) hv[m][n] = MFMA16(xa[m], wvB[n][ks], hv[m][n]);
      }
#pragma unroll
      for (int m = 0; m < 4; ++m)
#pragma unroll
        for (int n = 0; n < 2; ++n) {
          int d = w * 32 + n * 16 + l16;
          int key0 = m * 16 + l4 * 4;
          float v0 = fmaxf(hv[m][n][0] + bvB[n], 0.f);
          float v1 = fmaxf(hv[m][n][1] + bvB[n], 0.f);
          float v2 = fmaxf(hv[m][n][2] + bvB[n], 0.f);
          float v3 = fmaxf(hv[m][n][3] + bvB[n], 0.f);
          uint2 o; o.x = pk2(v0, v1); o.y = pk2(v2, v3);
          *(uint2*)&HB[d * PV + key0] = o;
        }
    }
    // NO barrier: G3 reads only rows w*32..w*32+31 of HvT, written by this
    // same wave; DS ops are in-order per wave. Cross-wave HB reuse is guarded
    // by next iteration's b1.

    // ---- G3: ACC += P^T @ Hv ----
#pragma unroll
    for (int ks = 0; ks < 2; ++ks) {
      bf8 pa[6];
#pragma unroll
      for (int m = 0; m < 6; ++m)
        pa[m] = *(const bf8*)&Pt[(m * 16 + l16) * PP + ks * 32 + l4 * 8];
#pragma unroll
      for (int n = 0; n < 2; ++n) {
        bf8 hb = *(const bf8*)&HB[(w * 32 + n * 16 + l16) * PV + ks * 32 + l4 * 8];
#pragma unroll
        for (int m = 0; m < 6; ++m) accO[m][n] = MFMA16(pa[m], hb, accO[m][n]);
      }
    }
    buf ^= 1;
  }

  // ---- write partial ACC (96x128 bf16) and partial l (96 fp32) ----
  u16* ap = accP + (size_t)(b * nchunk + chunk) * 96 * 128;
#pragma unroll
  for (int m = 0; m < 6; ++m)
#pragma unroll
    for (int n = 0; n < 2; ++n) {
      int d = w * 32 + n * 16 + l16;
#pragma unroll
      for (int r = 0; r < 4; ++r) {
        int hq = m * 16 + l4 * 4 + r;
        ap[hq * 128 + d] = f2bf(accO[m][n][r]);
      }
    }
  if (l4 == 0) {
#pragma unroll
    for (int n = 0; n < 6; ++n) lred[w * 96 + n * 16 + l16] = lacc[n];
  }
  __syncthreads();
  if (t < 96) {
    float s = lred[t] + lred[96 + t] + lred[192 + t] + lred[288 + t];
    lP[(size_t)(b * nchunk + chunk) * 96 + t] = s;
  }
}

// ---------------- patch body (device fn) -------------------------------------

__device__ __forceinline__ void patch_body(char* smem, int bt, int kc,
    const float* __restrict__ X, const u16* __restrict__ peB,
    u16* __restrict__ patchP) {
  u16* Xp = (u16*)smem;                 // 64*136
  u16* Wt = (u16*)(smem + 17408);       // 128*128, XOR-swizzled slot ^= co&7
  int t = threadIdx.x;
  int l = t & 63, w = t >> 6;
  int l16 = l & 15, l4 = l >> 4;
  const float* Xbt = X + (size_t)bt * 524288 + (size_t)kc * 65536;

  f4v acc[4][2];
#pragma unroll
  for (int m = 0; m < 4; ++m)
#pragma unroll
    for (int n = 0; n < 2; ++n) acc[m][n] = (f4v){0.f, 0.f, 0.f, 0.f};

  float4 xr[8];
  auto loadX = [&](int s) {
    const float* img = Xbt + (size_t)s * 8192;
#pragma unroll
    for (int r = 0; r < 8; ++r) xr[r] = *(const float4*)(img + (r * 256 + t) * 4);
  };
  loadX(0);

  for (int s = 0; s < 8; ++s) {
#pragma unroll
    for (int r = 0; r < 8; ++r) {
      int idx = (r * 256 + t) * 4;
      int cl = idx >> 12, off = idx & 4095;
      int h = off >> 6, w0 = off & 63;
      int patch = (h >> 3) * 8 + (w0 >> 3);
      int within = (h & 7) * 8 + (w0 & 7);
      uint2 o; o.x = pk2(xr[r].x, xr[r].y); o.y = pk2(xr[r].z, xr[r].w);
      *(uint2*)&Xp[patch * 136 + cl * 64 + within] = o;
    }
    {
      int colbase = kc * 1024 + s * 128;
#pragma unroll
      for (int r = 0; r < 8; ++r) {
        int idx = r * 256 + t;
        int co = idx >> 4, part = idx & 15;
        int slot = part ^ (co & 7);
        uint4 v = *(const uint4*)(peB + (size_t)co * 8192 + colbase + part * 8);
        *(uint4*)&Wt[co * 128 + slot * 8] = v;
      }
    }
    if (s < 7) loadX(s + 1);
    __syncthreads();
#pragma unroll
    for (int ks2 = 0; ks2 < 4; ++ks2) {
      bf8 af[4];
#pragma unroll
      for (int m = 0; m < 4; ++m)
        af[m] = *(const bf8*)&Xp[(m * 16 + l16) * 136 + ks2 * 32 + l4 * 8];
#pragma unroll
      for (int n = 0; n < 2; ++n) {
        int co = w * 32 + n * 16 + l16;
        int slot = (ks2 * 4 + l4) ^ (co & 7);
        bf8 bf_ = *(const bf8*)&Wt[co * 128 + slot * 8];
#pragma unroll
        for (int m = 0; m < 4; ++m) acc[m][n] = MFMA16(af[m], bf_, acc[m][n]);
      }
    }
    __syncthreads();
  }
  u16* outp = patchP + ((size_t)kc * 6144 + bt * 64) * 128;
#pragma unroll
  for (int m = 0; m < 4; ++m)
#pragma unroll
    for (int n = 0; n < 2; ++n) {
      int d = w * 32 + n * 16 + l16;
#pragma unroll
      for (int r = 0; r < 4; ++r) {
        int patch = m * 16 + l4 * 4 + r;
        outp[patch * 128 + d] = f2bf(acc[m][n][r]);
      }
    }
}

// ---------------- ogred body (device fn) -------------------------------------

__device__ __forceinline__ void ogred_body(char* smem, int t, int b, int nchunk,
    const u16* __restrict__ accP, const float* __restrict__ lP,
    const float* __restrict__ Wvo, const float* __restrict__ bvo,
    float* __restrict__ og) {
  float* op = (float*)smem;             // 512 f
  float* invl = (float*)(smem + 2048);  // 4 f
  int tid = threadIdx.x;
  for (int p = tid; p < 512; p += 256) {
    int h = p >> 7, e = p & 127;
    const u16* src = accP + ((size_t)b * nchunk * 96 + h * 24 + t) * 128 + e;
    float s = 0.f;
    for (int c = 0; c < nchunk; ++c) s += bflo((unsigned)src[(size_t)c * 12288]);
    op[p] = s;
  }
  if (tid < 4) {
    const float* lp = lP + (size_t)b * nchunk * 96 + tid * 24 + t;
    float ls = 0.f;
    for (int c = 0; c < nchunk; ++c) ls += lp[(size_t)c * 96];
    invl[tid] = 1.f / ls;
  }
  __syncthreads();
  for (int p = tid; p < 512; p += 256) op[p] *= invl[p >> 7];
  __syncthreads();
  if (tid < 128) {
    int e = tid;
    float acc = bvo[e];
    for (int h = 0; h < 4; ++h)
      for (int j = 0; j < 128; ++j) acc += op[h * 128 + j] * Wvo[(h * 128 + j) * 128 + e];
    og[(b * 24 + t) * 128 + e] = acc;
  }
}

// ---------------- K3: flash64 || patch ---------------------------------------

__global__ __launch_bounds__(256, 2) void k_big1(
    const float* __restrict__ gf, const u16* __restrict__ W1c_g,
    const float* __restrict__ gek_b1, const float* __restrict__ gev_b1,
    const u16* __restrict__ PkT_g, const float* __restrict__ ck_g,
    u16* __restrict__ accP_g, float* __restrict__ lP_g,
    const float* __restrict__ gridf, const u16* __restrict__ peB,
    u16* __restrict__ patchP) {
  __shared__ __align__(16) char smem[78336];
  int x = blockIdx.x;                   // 1280 blocks, 2:3 interleave
  int r5 = x % 5, q5 = x / 5;
  if (r5 < 2) {
    int fid = q5 * 2 + r5;              // 0..511
    flash_body<64, 1, false>(smem, gf, (const float*)nullptr, 0,
        W1c_g, gek_b1, gev_b1, PkT_g, ck_g, accP_g, lP_g,
        49152, 384, fid & 127, fid >> 7, 128);
  } else {
    int pid = q5 * 3 + (r5 - 2);        // 0..767
    patch_body(smem, pid % 96, pid / 96, gridf, peB, patchP);
  }
}

// ---------------- K4: ogred_graph || flash128 --------------------------------

__global__ __launch_bounds__(256, 2) void k_big2(
    const u16* __restrict__ accP_g, const float* __restrict__ lP_g,
    const float* __restrict__ Wvo_g, const float* __restrict__ bvo_g,
    float* __restrict__ og_g,
    const u16* __restrict__ patchP, const float* __restrict__ pe_b,
    const u16* __restrict__ W1c_r,
    const float* __restrict__ rk_b1, const float* __restrict__ rv_b1,
    const u16* __restrict__ PkT_r, const float* __restrict__ ck_r,
    u16* __restrict__ accP_r, float* __restrict__ lP_r) {
  __shared__ __align__(16) char smem[94720];
  int x = blockIdx.x;                   // 192 blocks
  int id = x >> 1;
  if (x & 1) {
    flash_body<128, 8, true>(smem, patchP, pe_b, 786432,
        W1c_r, rk_b1, rv_b1, PkT_r, ck_r, accP_r, lP_r,
        1536, 64, id % 24, id / 24, 24);
  } else {
    ogred_body(smem, id % 24, id / 24, 128, accP_g, lP_g, Wvo_g, bvo_g, og_g);
  }
}

// ---------------- K5: ogred_grid || g_out writer -----------------------------

__global__ __launch_bounds__(256) void k_big3(
    const u16* __restrict__ accP_r, const float* __restrict__ lP_r,
    const float* __restrict__ Wvo_r, const float* __restrict__ bvo_r,
    float* __restrict__ og_r,
    const float* __restrict__ og_g, float* __restrict__ outg) {
  __shared__ __align__(16) char smem[2064];
  int x = blockIdx.x;                   // 96 + 4096 blocks
  if (x < 96) {
    ogred_body(smem, x % 24, x / 24, 24, accP_r, lP_r, Wvo_r, bvo_r, og_r);
  } else {
    int vx = x - 96;
    int b = vx >> 10;
    const float* ogb = og_g + b * 3072;
    float* ob = outg + (size_t)b * 6291456;
    for (int i4 = (vx & 1023) * 256 + threadIdx.x; i4 < 1572864; i4 += 1024 * 256) {
      int i = i4 * 4;
      int n = i >> 7, e = i & 127;
      float src = fmaxf((n + 0.5f) * (1.f / 2048.f) - 0.5f, 0.f);
      int t0 = (int)src; float lam = src - (float)t0; int t1 = min(t0 + 1, 23);
      float4 a = *(const float4*)&ogb[t0 * 128 + e];
      float4 c = *(const float4*)&ogb[t1 * 128 + e];
      float4 o;
      o.x = a.x + lam * (c.x - a.x); o.y = a.y + lam * (c.y - a.y);
      o.z = a.z + lam * (c.z - a.z); o.w = a.w + lam * (c.w - a.w);
      *(float4*)&ob[i] = o;
    }
  }
}

// ---------------- K6: fused U-GEMM + up lerp-upsample writer -----------------
// block = (b, o): U_s[τ][pq] = og_r[b,τ,:]·up_w[:,o,pq] + up_b[o] in LDS,
// then write out[b, :, o, :, :] (24*4096 floats) with temporal lerp.

__global__ __launch_bounds__(256) void k_upfuse(const float* __restrict__ og_r,
    const float* __restrict__ up_w, const float* __restrict__ up_b,
    float* __restrict__ outu) {
  int b = blockIdx.x >> 7, o = blockIdx.x & 127;
  __shared__ float og_s[24 * 128];      // 12 KB
  __shared__ float upw_s[128 * 64];     // 32 KB  [c][pq]
  __shared__ float U_s[24 * 64];        // 6 KB
  int tid = threadIdx.x;
  for (int i = tid; i < 24 * 128 / 4; i += 256)
    ((float4*)og_s)[i] = ((const float4*)(og_r + b * 3072))[i];
  for (int i = tid; i < 128 * 64 / 4; i += 256) {
    int c = i >> 4, pq4 = i & 15;
    ((float4*)upw_s)[i] = *(const float4*)(up_w + (size_t)c * 8192 + o * 64 + pq4 * 4);
  }
  __syncthreads();
  float bias = up_b[o];
  int pq = tid & 63, tg = tid >> 6;     // 4 groups x 6 tau
  float acc[6] = {0.f, 0.f, 0.f, 0.f, 0.f, 0.f};
  for (int c = 0; c < 128; c += 4) {
    float w0 = upw_s[c * 64 + pq], w1 = upw_s[(c + 1) * 64 + pq];
    float w2 = upw_s[(c + 2) * 64 + pq], w3 = upw_s[(c + 3) * 64 + pq];
#pragma unroll
    for (int r = 0; r < 6; ++r) {
      float4 g = *(const float4*)&og_s[(tg * 6 + r) * 128 + c];
      acc[r] += g.x * w0 + g.y * w1 + g.z * w2 + g.w * w3;
    }
  }
#pragma unroll
  for (int r = 0; r < 6; ++r) U_s[(tg * 6 + r) * 64 + pq] = acc[r] + bias;
  __syncthreads();
  for (int i4 = tid; i4 < 24 * 1024; i4 += 256) {
    int i = i4 * 4;                     // t*4096 + h*64 + w0
    int t = i >> 12, hw = i & 4095;
    int h = hw >> 6, w0 = hw & 63;
    int ii = h >> 3, p = h & 7, j = w0 >> 3, q0 = w0 & 7;
    int n = t * 64 + ii * 8 + j;
    float src = fmaxf((n + 0.5f) * (1.f / 64.f) - 0.5f, 0.f);
    int t0 = (int)src; float lam = src - (float)t0; int t1 = min(t0 + 1, 23);
    float4 a = *(const float4*)&U_s[t0 * 64 + p * 8 + q0];
    float4 c4 = *(const float4*)&U_s[t1 * 64 + p * 8 + q0];
    float4 r;
    r.x = a.x + lam * (c4.x - a.x); r.y = a.y + lam * (c4.y - a.y);
    r.z = a.z + lam * (c4.z - a.z); r.w = a.w + lam * (c4.w - a.w);
    *(float4*)&outu[((size_t)(b * 24 + t) * 128 + o) * 4096 + hw] = r;
  }
}

// ---------------------------------------------------------------------------

extern "C" void kernel_launch(void* const* d_in, const int* in_sizes, int n_in,
                              void* d_out, int out_size, void* d_ws, size_t ws_size,
                              hipStream_t stream) {
  (void)in_sizes; (void)n_in; (void)out_size; (void)ws_size;
  const float* gf    = (const float*)d_in[0];
  const float* gridf = (const float*)d_in[1];
  const float* gti   = (const float*)d_in[2];
  const float* gek_w1 = (const float*)d_in[4],  *gek_b1 = (const float*)d_in[5];
  const float* gek_w2 = (const float*)d_in[6],  *gek_b2 = (const float*)d_in[7];
  const float* gev_w1 = (const float*)d_in[8],  *gev_b1 = (const float*)d_in[9];
  const float* gev_w2 = (const float*)d_in[10], *gev_b2 = (const float*)d_in[11];
  const float* rk_w1  = (const float*)d_in[12], *rk_b1  = (const float*)d_in[13];
  const float* rk_w2  = (const float*)d_in[14], *rk_b2  = (const float*)d_in[15];
  const float* rv_w1  = (const float*)d_in[16], *rv_b1  = (const float*)d_in[17];
  const float* rv_w2  = (const float*)d_in[18], *rv_b2  = (const float*)d_in[19];
  const float* te_w1  = (const float*)d_in[20], *te_b1  = (const float*)d_in[21];
  const float* te_w2  = (const float*)d_in[22], *te_b2  = (const float*)d_in[23];
  const float* pe_w   = (const float*)d_in[24], *pe_b   = (const float*)d_in[25];
  const float* up_w   = (const float*)d_in[26], *up_b   = (const float*)d_in[27];
  const float* ag_q_w = (const float*)d_in[28], *ag_q_b = (const float*)d_in[29];
  const float* ag_k_w = (const float*)d_in[30], *ag_k_b = (const float*)d_in[31];
  const float* ag_v_w = (const float*)d_in[32], *ag_v_b = (const float*)d_in[33];
  const float* ag_o_w = (const float*)d_in[34], *ag_o_b = (const float*)d_in[35];
  const float* ar_q_w = (const float*)d_in[36], *ar_q_b = (const float*)d_in[37];
  const float* ar_k_w = (const float*)d_in[38], *ar_k_b = (const float*)d_in[39];
  const float* ar_v_w = (const float*)d_in[40], *ar_v_b = (const float*)d_in[41];
  const float* ar_o_w = (const float*)d_in[42], *ar_o_b = (const float*)d_in[43];

  float* out = (float*)d_out;          // g_out (25165824 f) then up (50331648 f)
  float* ws = (float*)d_ws;
  size_t off = 0;
  auto A = [&](size_t n) { float* p = ws + off; off += n; return p; };
  float* q_g   = A(12288);   float* q_r   = A(12288);
  float* Wk_g  = A(16384);   float* bk_g  = A(128);
  float* Wv_g  = A(16384);   float* bv_g  = A(128);
  float* Wk_r  = A(16384);   float* bk_r  = A(128);
  float* Wv_r  = A(16384);   float* bv_r  = A(128);
  float* Wvo_g = A(65536);   float* bvo_g = A(128);
  float* Wvo_r = A(65536);   float* bvo_r = A(128);
  float* ck_g  = A(384);     float* ck_r  = A(384);
  u16*   PkT_g = (u16*)A(26112);   // 4*96*136 bf16
  u16*   PkT_r = (u16*)A(26112);
  u16*   W1c_g = (u16*)A(8192);    // 256*64 bf16
  u16*   W1c_r = (u16*)A(16384);   // 256*128 bf16
  u16*   peB   = (u16*)A(524288);  // 128*8192 bf16
  float* lP_g  = A(49152);   float* lP_r  = A(9216);
  float* og_g  = A(12288);   float* og_r  = A(12288);
  u16*   accP_g = (u16*)A(3145728);   // 4*128*12288 bf16
  u16*   patchP = (u16*)A(3145728);   // 8*6144*128 bf16
  u16*   accP_r = (u16*)A(589824);    // 4*24*12288 bf16

  k_pre1<<<2148, 128, 0, stream>>>(
      gek_w1, gev_w1, rk_w1, rv_w1, W1c_g, W1c_r,
      pe_w, peB,
      gti, te_w1, te_b1, te_w2, te_b2, ag_q_w, ag_q_b, ar_q_w, ar_q_b, q_g, q_r,
      gek_w2, gek_b2, ag_k_w, ag_k_b, Wk_g, bk_g,
      gev_w2, gev_b2, ag_v_w, ag_v_b, Wv_g, bv_g,
      rk_w2,  rk_b2,  ar_k_w, ar_k_b, Wk_r, bk_r,
      rv_w2,  rv_b2,  ar_v_w, ar_v_b, Wv_r, bv_r);
  k_wvopk<<<dim3(129, 16), 128, 0, stream>>>(
      Wv_g, bv_g, ag_o_w, ag_o_b, Wvo_g, bvo_g,
      Wv_r, bv_r, ar_o_w, ar_o_b, Wvo_r, bvo_r,
      Wk_g, bk_g, q_g, PkT_g, ck_g,
      Wk_r, bk_r, q_r, PkT_r, ck_r);

  // K3: graph flash (512 virtual blocks) || patch conv (768 virtual blocks)
  k_big1<<<1280, 256, 0, stream>>>(
      gf, W1c_g, gek_b1, gev_b1, PkT_g, ck_g, accP_g, lP_g,
      gridf, peB, patchP);
  // K4: graph chunk-reduce+og (96) || grid flash (96)
  k_big2<<<192, 256, 0, stream>>>(
      accP_g, lP_g, Wvo_g, bvo_g, og_g,
      patchP, pe_b, W1c_r, rk_b1, rv_b1, PkT_r, ck_r, accP_r, lP_r);
  // K5: grid chunk-reduce+og (96) || g_out writer (4096)
  k_big3<<<4192, 256, 0, stream>>>(
      accP_r, lP_r, Wvo_r, bvo_r, og_r, og_g, out);
  // K6: U-GEMM + upsample writer
  k_upfuse<<<512, 256, 0, stream>>>(og_r, up_w, up_b, out + 25165824);
}

// Round 7
// 213.457 us; speedup vs baseline: 2.2641x; 1.1066x over previous
//
#include <hip/hip_runtime.h>

// ---------------------------------------------------------------------------
// GraphGridCrossAttnModel — round 7: tail attack.
//   K1 pre1 | K2 wvopk | K3 {flash64 || patch} | K4 {ogred_g || flash128}
//   K5 ogred_r | K6 {upfuse || gout}
// ogred: uint4-vectorized chunk reduce + full-block GEMM (was scalar u16 +
// half-idle). Writers merged into one HBM-write-bound dispatch.
// MFMA layout (16x16x32 bf16, m89-verified):
//  A: m=l&15, k=(l>>4)*8+j ; B: n=l&15, k=(l>>4)*8+j ; D: col=l&15, row=(l>>4)*4+reg
// ---------------------------------------------------------------------------

typedef unsigned short u16;
using bf8 = __attribute__((ext_vector_type(8))) short;
using f4v = __attribute__((ext_vector_type(4))) float;
#define MFMA16(a, b, c) __builtin_amdgcn_mfma_f32_16x16x32_bf16(a, b, c, 0, 0, 0)

constexpr float INV_SCALE = 0.17677669529663687f;   // 1/sqrt(32)

__device__ __forceinline__ u16 f2bf(float f) {
  unsigned u = __float_as_uint(f);
  u += 0x7FFFu + ((u >> 16) & 1u);
  return (u16)(u >> 16);
}
__device__ __forceinline__ unsigned pk2(float a, float b) {
  return (unsigned)f2bf(a) | ((unsigned)f2bf(b) << 16);
}
__device__ __forceinline__ float bflo(unsigned v) { return __uint_as_float(v << 16); }
__device__ __forceinline__ float bfhi(unsigned v) { return __uint_as_float(v & 0xffff0000u); }

// ---------------- K1: fused precompute: w1c | cvt | teq | fold ---------------

__global__ __launch_bounds__(128) void k_pre1(
    const float* gk_w1, const float* gv_w1, const float* rk_w1, const float* rv_w1,
    u16* W1c_g, u16* W1c_r,
    const float* pe_w, u16* peB,
    const float* tidx, const float* te_w1, const float* te_b1,
    const float* te_w2, const float* te_b2,
    const float* wg, const float* bg, const float* wr, const float* br,
    float* qg, float* qr,
    const float* A0, const float* Ab0, const float* B0, const float* Bb0, float* O0, float* Ob0,
    const float* A1, const float* Ab1, const float* B1, const float* Bb1, float* O1, float* Ob1,
    const float* A2, const float* Ab2, const float* B2, const float* Bb2, float* O2, float* Ob2,
    const float* A3, const float* Ab3, const float* B3, const float* Bb3, float* O3, float* Ob3) {
  int x = blockIdx.x, e = threadIdx.x;
  __shared__ float sh[256];
  if (x < 512) {                    // --- W1c bf16 transpose-pack
    int c = x & 255, brn = x >> 8;
    int DIN = brn ? 128 : 64;
    if (e < DIN) {
      const float* src = brn ? (c < 128 ? rk_w1 : rv_w1) : (c < 128 ? gk_w1 : gv_w1);
      u16* dst = brn ? W1c_r : W1c_g;
      dst[c * DIN + e] = f2bf(src[e * 128 + (c & 127)]);
    }
  } else if (x < 1536) {            // --- pe_w -> bf16
    int i = ((x - 512) * 128 + e) * 8;
    float4 v0 = *(const float4*)(pe_w + i);
    float4 v1 = *(const float4*)(pe_w + i + 4);
    uint4 o; o.x = pk2(v0.x, v0.y); o.y = pk2(v0.z, v0.w);
    o.z = pk2(v1.x, v1.y); o.w = pk2(v1.z, v1.w);
    *(uint4*)&peB[i] = o;
  } else if (x < 1632) {            // --- te -> q_g/q_r
    int row = x - 1536;
    float tv = tidx[row];
    sh[e] = fmaxf(tv * te_w1[e] + te_b1[e], 0.f);
    __syncthreads();
    float a = te_b2[e];
    for (int j = 0; j < 128; ++j) a += sh[j] * te_w2[j * 128 + e];
    sh[128 + e] = a;
    __syncthreads();
    float ag = bg[e], ar = br[e];
    for (int j = 0; j < 128; ++j) {
      float xx = sh[128 + j];
      ag += xx * wg[j * 128 + e];
      ar += xx * wr[j * 128 + e];
    }
    qg[row * 128 + e] = ag;
    qr[row * 128 + e] = ar;
  } else {                          // --- fold W2@Wqkv
    int sub = x - 1632;
    int task = sub / 129, j = sub % 129;
    const float *A, *Ab, *Bm, *Bb; float *O, *Ob;
    switch (task) {
      case 0: A=A0; Ab=Ab0; Bm=B0; Bb=Bb0; O=O0; Ob=Ob0; break;
      case 1: A=A1; Ab=Ab1; Bm=B1; Bb=Bb1; O=O1; Ob=Ob1; break;
      case 2: A=A2; Ab=Ab2; Bm=B2; Bb=Bb2; O=O2; Ob=Ob2; break;
      default:A=A3; Ab=Ab3; Bm=B3; Bb=Bb3; O=O3; Ob=Ob3; break;
    }
    sh[e] = (j < 128) ? A[j * 128 + e] : Ab[e];
    __syncthreads();
    float acc = (j < 128) ? 0.f : Bb[e];
    for (int m = 0; m < 128; ++m) acc += sh[m] * Bm[m * 128 + e];
    if (j < 128) O[j * 128 + e] = acc; else Ob[e] = acc;
  }
}

// ---------------- K2: merged Wvo/bvo + PkT/ck --------------------------------

__global__ __launch_bounds__(128) void k_wvopk(
    const float* Wv_g, const float* bv_g, const float* ow_g, const float* ob_g, float* Wvo_g, float* bvo_g,
    const float* Wv_r, const float* bv_r, const float* ow_r, const float* ob_r, float* Wvo_r, float* bvo_r,
    const float* Wk_g, const float* bk_g, const float* q_g, u16* PkT_g, float* ck_g,
    const float* Wk_r, const float* bk_r, const float* q_r, u16* PkT_r, float* ck_r) {
  int j = blockIdx.x, e = threadIdx.x;
  if (blockIdx.y < 8) {
    int br = blockIdx.y >> 2, h = blockIdx.y & 3;
    const float* Wv = br ? Wv_r : Wv_g;  const float* bv = br ? bv_r : bv_g;
    const float* ow = br ? ow_r : ow_g;  const float* ob = br ? ob_r : ob_g;
    float* Wvo = br ? Wvo_r : Wvo_g;     float* bvo = br ? bvo_r : bvo_g;
    if (j < 128) {
      __shared__ float wrow[32];
      if (e < 32) wrow[e] = Wv[j * 128 + h * 32 + e];
      __syncthreads();
      float acc = 0.f;
      for (int d = 0; d < 32; ++d) acc += wrow[d] * ow[(h * 32 + d) * 128 + e];
      Wvo[(h * 128 + j) * 128 + e] = acc;
    } else if (h == 0) {
      __shared__ float bbv[128];
      bbv[e] = bv[e];
      __syncthreads();
      float acc = ob[e];
      for (int m = 0; m < 128; ++m) acc += bbv[m] * ow[m * 128 + e];
      bvo[e] = acc;
    }
  } else {
    int y = blockIdx.y - 8;
    int br = y >> 2, b = y & 3;
    int hq = e;
    if (hq >= 96) return;
    const float* Wk = br ? Wk_r : Wk_g;  const float* bk = br ? bk_r : bk_g;
    const float* q  = br ? q_r  : q_g;
    u16* PkT = br ? PkT_r : PkT_g;       float* ck = br ? ck_r : ck_g;
    int h = hq / 24, t = hq % 24;
    const float* qrow = q + (b * 24 + t) * 128 + h * 32;
    if (j < 128) {
      const float* wrow = Wk + j * 128 + h * 32;
      float acc = 0.f;
      for (int d = 0; d < 32; ++d) acc += wrow[d] * qrow[d];
      PkT[((size_t)b * 96 + hq) * 136 + j] = f2bf(acc * INV_SCALE);
    } else {
      float acc = 0.f;
      for (int d = 0; d < 32; ++d) acc += bk[h * 32 + d] * qrow[d];
      ck[b * 96 + hq] = acc * INV_SCALE;
    }
  }
}

// ---------------- flash body (device fn, LDS carved from smem) ---------------
// 4 waves; 64-key tiles; Xt double-buffered; 3 barriers/tile.

template <int DIN, int NRED, bool INBF>
__device__ __forceinline__ void flash_body(char* smem,
    const void* __restrict__ Xv, const float* __restrict__ redbias, size_t rstride,
    const u16* __restrict__ W1c, const float* __restrict__ b1k, const float* __restrict__ b1v,
    const u16* __restrict__ PkT, const float* __restrict__ ck,
    u16* __restrict__ accP, float* __restrict__ lP,
    int KL, int kpb, int chunk, int b, int nchunk) {
  constexpr int KS = DIN / 32;
  constexpr int PD = DIN + 8;
  constexpr int PH = 136, PV = 72, PP = 72;
  constexpr int NR = DIN / 16;
  constexpr int XTN = 64 * PD;                  // u16 per Xt buffer
  u16* Xt   = (u16*)smem;                       // [2][XTN]
  u16* HB   = (u16*)(smem + 4 * XTN);           // 9216 u16
  u16* Pt   = (u16*)(smem + 4 * XTN + 18432);   // 96*72
  u16* Pk_s = (u16*)(smem + 4 * XTN + 18432 + 13824);   // 96*136
  float* lred = (float*)(smem + 4 * XTN + 18432 + 13824 + 26112);  // 384 f

  int t = threadIdx.x;
  int l = t & 63, w = t >> 6;
  int l16 = l & 15, l4 = l >> 4;

  size_t xbase = (size_t)b * KL * DIN + (size_t)chunk * kpb * DIN;

  // stage PkT[b] into LDS (once per block)
  {
    const unsigned* ps = (const unsigned*)(PkT + (size_t)b * 96 * 136);
    unsigned* pd = (unsigned*)Pk_s;
    for (int i = t; i < 96 * 136 / 2; i += 256) pd[i] = ps[i];
  }

  bf8 wkA[2][KS], wvB[2][KS];
#pragma unroll
  for (int m = 0; m < 2; ++m)
#pragma unroll
    for (int ks = 0; ks < KS; ++ks) {
      int hid = w * 32 + m * 16 + l16;
      wkA[m][ks] = *(const bf8*)(W1c + (size_t)hid * DIN + ks * 32 + l4 * 8);
      wvB[m][ks] = *(const bf8*)(W1c + (size_t)(128 + hid) * DIN + ks * 32 + l4 * 8);
    }
  float bkA[2][4], bvB[2], ckr[6];
#pragma unroll
  for (int m = 0; m < 2; ++m)
#pragma unroll
    for (int r = 0; r < 4; ++r) bkA[m][r] = b1k[w * 32 + m * 16 + l4 * 4 + r];
#pragma unroll
  for (int n = 0; n < 2; ++n) bvB[n] = b1v[w * 32 + n * 16 + l16];
#pragma unroll
  for (int n = 0; n < 6; ++n) ckr[n] = ck[b * 96 + n * 16 + l16];

  f4v accO[6][2];
#pragma unroll
  for (int m = 0; m < 6; ++m)
#pragma unroll
    for (int n = 0; n < 2; ++n) accO[m][n] = (f4v){0.f, 0.f, 0.f, 0.f};
  float lacc[6] = {0.f, 0.f, 0.f, 0.f, 0.f, 0.f};

  float4 xr[NR];
  auto load_tile = [&](int kt) {
#pragma unroll
    for (int r = 0; r < NR; ++r) {
      int idx = (r * 256 + t) * 4;
      if constexpr (!INBF) {
        const float* Xrow = (const float*)Xv + xbase + (size_t)kt * 64 * DIN;
        xr[r] = *(const float4*)(Xrow + idx);
      } else {
        const u16* Xrow = (const u16*)Xv + xbase + (size_t)kt * 64 * DIN;
        int din = idx % DIN;
        float4 a = *(const float4*)(redbias + din);
#pragma unroll
        for (int c = 0; c < NRED; ++c) {
          uint2 v = *(const uint2*)(Xrow + (size_t)c * rstride + idx);
          a.x += bflo(v.x); a.y += bfhi(v.x);
          a.z += bflo(v.y); a.w += bfhi(v.y);
        }
        xr[r] = a;
      }
    }
  };

  int ntile = kpb >> 6;
  load_tile(0);
  int buf = 0;
  for (int kt = 0; kt < ntile; ++kt) {
    // ---- write staged tile (regs -> LDS bf16), prefetch next ----
#pragma unroll
    for (int r = 0; r < NR; ++r) {
      int idx = (r * 256 + t) * 4;
      int key = idx / DIN, din = idx % DIN;
      uint2 o; o.x = pk2(xr[r].x, xr[r].y); o.y = pk2(xr[r].z, xr[r].w);
      *(uint2*)&Xt[buf * XTN + key * PD + din] = o;
    }
    if (kt + 1 < ntile) load_tile(kt + 1);
    __syncthreads();                                   // b1 (Xt ready; HB free)

    // ---- G1a: Hk = W1k^T @ X^T ----
    {
      f4v hk[2][4];
#pragma unroll
      for (int m = 0; m < 2; ++m)
#pragma unroll
        for (int n = 0; n < 4; ++n) hk[m][n] = (f4v){0.f, 0.f, 0.f, 0.f};
#pragma unroll
      for (int ks = 0; ks < KS; ++ks) {
        bf8 xf[4];
#pragma unroll
        for (int n = 0; n < 4; ++n)
          xf[n] = *(const bf8*)&Xt[buf * XTN + (n * 16 + l16) * PD + ks * 32 + l4 * 8];
#pragma unroll
        for (int m = 0; m < 2; ++m)
#pragma unroll
          for (int n = 0; n < 4; ++n) hk[m][n] = MFMA16(wkA[m][ks], xf[n], hk[m][n]);
      }
#pragma unroll
      for (int m = 0; m < 2; ++m)
#pragma unroll
        for (int n = 0; n < 4; ++n) {
          int key = n * 16 + l16;
          int hid0 = w * 32 + m * 16 + l4 * 4;
          float v0 = fmaxf(hk[m][n][0] + bkA[m][0], 0.f);
          float v1 = fmaxf(hk[m][n][1] + bkA[m][1], 0.f);
          float v2 = fmaxf(hk[m][n][2] + bkA[m][2], 0.f);
          float v3 = fmaxf(hk[m][n][3] + bkA[m][3], 0.f);
          uint2 o; o.x = pk2(v0, v1); o.y = pk2(v2, v3);
          *(uint2*)&HB[key * PH + hid0] = o;
        }
    }
    __syncthreads();                                   // b2 (Hk ready)

    // ---- G2: S = Hk @ Pk ----
    {
      f4v sa[6];
#pragma unroll
      for (int n = 0; n < 6; ++n) sa[n] = (f4v){ckr[n], ckr[n], ckr[n], ckr[n]};
#pragma unroll
      for (int ks = 0; ks < 4; ++ks) {
        bf8 a = *(const bf8*)&HB[(w * 16 + l16) * PH + ks * 32 + l4 * 8];
#pragma unroll
        for (int n = 0; n < 6; ++n) {
          bf8 bp = *(const bf8*)&Pk_s[(n * 16 + l16) * 136 + ks * 32 + l4 * 8];
          sa[n] = MFMA16(a, bp, sa[n]);
        }
      }
#pragma unroll
      for (int n = 0; n < 6; ++n) {
        float e0 = __expf(sa[n][0]), e1 = __expf(sa[n][1]);
        float e2 = __expf(sa[n][2]), e3 = __expf(sa[n][3]);
        float ls = (e0 + e1) + (e2 + e3);
        ls += __shfl_xor(ls, 16);
        ls += __shfl_xor(ls, 32);
        lacc[n] += ls;
        uint2 o; o.x = pk2(e0, e1); o.y = pk2(e2, e3);
        *(uint2*)&Pt[(n * 16 + l16) * PP + w * 16 + l4 * 4] = o;
      }
    }
    __syncthreads();                                   // b3 (Pt ready; HB-k readers done)

    // ---- G1b: Hv = X @ W1v -> HvT[hid][key] (own-wave rows) ----
    {
      f4v hv[4][2];
#pragma unroll
      for (int m = 0; m < 4; ++m)
#pragma unroll
        for (int n = 0; n < 2; ++n) hv[m][n] = (f4v){0.f, 0.f, 0.f, 0.f};
#pragma unroll
      for (int ks = 0; ks < KS; ++ks) {
        bf8 xa[4];
#pragma unroll
        for (int m = 0; m < 4; ++m)
          xa[m] = *(const bf8*)&Xt[buf * XTN + (m * 16 + l16) * PD + ks * 32 + l4 * 8];
#pragma unroll
        for (int m = 0; m < 4; ++m)
#pragma unroll
          for (int n = 0; n < 2; ++n) hv[m][n] = MFMA16(xa[m], wvB[n][ks], hv[m][n]);
      }
#pragma unroll
      for (int m = 0; m < 4; ++m)
#pragma unroll
        for (int n = 0; n < 2; ++n) {
          int d = w * 32 + n * 16 + l16;
          int key0 = m * 16 + l4 * 4;
          float v0 = fmaxf(hv[m][n][0] + bvB[n], 0.f);
          float v1 = fmaxf(hv[m][n][1] + bvB[n], 0.f);
          float v2 = fmaxf(hv[m][n][2] + bvB[n], 0.f);
          float v3 = fmaxf(hv[m][n][3] + bvB[n], 0.f);
          uint2 o; o.x = pk2(v0, v1); o.y = pk2(v2, v3);
          *(uint2*)&HB[d * PV + key0] = o;
        }
    }
    // NO barrier: G3 reads only rows w*32..w*32+31 of HvT, written by this
    // same wave; DS ops are in-order per wave. Cross-wave HB reuse is guarded
    // by next iteration's b1.

    // ---- G3: ACC += P^T @ Hv ----
#pragma unroll
    for (int ks = 0; ks < 2; ++ks) {
      bf8 pa[6];
#pragma unroll
      for (int m = 0; m < 6; ++m)
        pa[m] = *(const bf8*)&Pt[(m * 16 + l16) * PP + ks * 32 + l4 * 8];
#pragma unroll
      for (int n = 0; n < 2; ++n) {
        bf8 hb = *(const bf8*)&HB[(w * 32 + n * 16 + l16) * PV + ks * 32 + l4 * 8];
#pragma unroll
        for (int m = 0; m < 6; ++m) accO[m][n] = MFMA16(pa[m], hb, accO[m][n]);
      }
    }
    buf ^= 1;
  }

  // ---- write partial ACC (96x128 bf16) and partial l (96 fp32) ----
  u16* ap = accP + (size_t)(b * nchunk + chunk) * 96 * 128;
#pragma unroll
  for (int m = 0; m < 6; ++m)
#pragma unroll
    for (int n = 0; n < 2; ++n) {
      int d = w * 32 + n * 16 + l16;
#pragma unroll
      for (int r = 0; r < 4; ++r) {
        int hq = m * 16 + l4 * 4 + r;
        ap[hq * 128 + d] = f2bf(accO[m][n][r]);
      }
    }
  if (l4 == 0) {
#pragma unroll
    for (int n = 0; n < 6; ++n) lred[w * 96 + n * 16 + l16] = lacc[n];
  }
  __syncthreads();
  if (t < 96) {
    float s = lred[t] + lred[96 + t] + lred[192 + t] + lred[288 + t];
    lP[(size_t)(b * nchunk + chunk) * 96 + t] = s;
  }
}

// ---------------- patch body (device fn) -------------------------------------

__device__ __forceinline__ void patch_body(char* smem, int bt, int kc,
    const float* __restrict__ X, const u16* __restrict__ peB,
    u16* __restrict__ patchP) {
  u16* Xp = (u16*)smem;                 // 64*136
  u16* Wt = (u16*)(smem + 17408);       // 128*128, XOR-swizzled slot ^= co&7
  int t = threadIdx.x;
  int l = t & 63, w = t >> 6;
  int l16 = l & 15, l4 = l >> 4;
  const float* Xbt = X + (size_t)bt * 524288 + (size_t)kc * 65536;

  f4v acc[4][2];
#pragma unroll
  for (int m = 0; m < 4; ++m)
#pragma unroll
    for (int n = 0; n < 2; ++n) acc[m][n] = (f4v){0.f, 0.f, 0.f, 0.f};

  float4 xr[8];
  auto loadX = [&](int s) {
    const float* img = Xbt + (size_t)s * 8192;
#pragma unroll
    for (int r = 0; r < 8; ++r) xr[r] = *(const float4*)(img + (r * 256 + t) * 4);
  };
  loadX(0);

  for (int s = 0; s < 8; ++s) {
#pragma unroll
    for (int r = 0; r < 8; ++r) {
      int idx = (r * 256 + t) * 4;
      int cl = idx >> 12, off = idx & 4095;
      int h = off >> 6, w0 = off & 63;
      int patch = (h >> 3) * 8 + (w0 >> 3);
      int within = (h & 7) * 8 + (w0 & 7);
      uint2 o; o.x = pk2(xr[r].x, xr[r].y); o.y = pk2(xr[r].z, xr[r].w);
      *(uint2*)&Xp[patch * 136 + cl * 64 + within] = o;
    }
    {
      int colbase = kc * 1024 + s * 128;
#pragma unroll
      for (int r = 0; r < 8; ++r) {
        int idx = r * 256 + t;
        int co = idx >> 4, part = idx & 15;
        int slot = part ^ (co & 7);
        uint4 v = *(const uint4*)(peB + (size_t)co * 8192 + colbase + part * 8);
        *(uint4*)&Wt[co * 128 + slot * 8] = v;
      }
    }
    if (s < 7) loadX(s + 1);
    __syncthreads();
#pragma unroll
    for (int ks2 = 0; ks2 < 4; ++ks2) {
      bf8 af[4];
#pragma unroll
      for (int m = 0; m < 4; ++m)
        af[m] = *(const bf8*)&Xp[(m * 16 + l16) * 136 + ks2 * 32 + l4 * 8];
#pragma unroll
      for (int n = 0; n < 2; ++n) {
        int co = w * 32 + n * 16 + l16;
        int slot = (ks2 * 4 + l4) ^ (co & 7);
        bf8 bf_ = *(const bf8*)&Wt[co * 128 + slot * 8];
#pragma unroll
        for (int m = 0; m < 4; ++m) acc[m][n] = MFMA16(af[m], bf_, acc[m][n]);
      }
    }
    __syncthreads();
  }
  u16* outp = patchP + ((size_t)kc * 6144 + bt * 64) * 128;
#pragma unroll
  for (int m = 0; m < 4; ++m)
#pragma unroll
    for (int n = 0; n < 2; ++n) {
      int d = w * 32 + n * 16 + l16;
#pragma unroll
      for (int r = 0; r < 4; ++r) {
        int patch = m * 16 + l4 * 4 + r;
        outp[patch * 128 + d] = f2bf(acc[m][n][r]);
      }
    }
}

// ---------------- ogred body (vectorized) ------------------------------------
// thread = (cq[4] x h[4] x oct[16]); uint4 loads (8 bf16); full-block GEMM.

__device__ __forceinline__ void ogred_body(char* smem, int t, int b, int nc,
    const u16* __restrict__ accP, const float* __restrict__ lP,
    const float* __restrict__ Wvo, const float* __restrict__ bvo,
    float* __restrict__ og) {
  float* part = (float*)smem;            // 2048 f
  float* invl = part + 2048;             // 4 f
  float* red  = part + 2052;             // 256 f
  int tid = threadIdx.x;
  int oct = tid & 15, h = (tid >> 4) & 3, cq = tid >> 6;
  int cn = nc >> 2;
  float a8[8];
#pragma unroll
  for (int k = 0; k < 8; ++k) a8[k] = 0.f;
  const u16* base = accP + ((size_t)(b * nc + cq * cn) * 96 + h * 24 + t) * 128 + oct * 8;
  for (int c = 0; c < cn; ++c) {
    uint4 v = *(const uint4*)(base + (size_t)c * 12288);
    a8[0] += bflo(v.x); a8[1] += bfhi(v.x);
    a8[2] += bflo(v.y); a8[3] += bfhi(v.y);
    a8[4] += bflo(v.z); a8[5] += bfhi(v.z);
    a8[6] += bflo(v.w); a8[7] += bfhi(v.w);
  }
#pragma unroll
  for (int k = 0; k < 8; ++k) part[cq * 512 + h * 128 + oct * 8 + k] = a8[k];
  if (tid < 64) {                        // l-sum: one wave, 16 lanes per head
    int hh = tid >> 4, c0 = tid & 15;
    float ls = 0.f;
    for (int c = c0; c < nc; c += 16) ls += lP[(size_t)(b * nc + c) * 96 + hh * 24 + t];
    ls += __shfl_xor(ls, 8); ls += __shfl_xor(ls, 4);
    ls += __shfl_xor(ls, 2); ls += __shfl_xor(ls, 1);
    if (c0 == 0) invl[hh] = 1.f / ls;
  }
  __syncthreads();
  for (int p = tid; p < 512; p += 256) {
    float s = (part[p] + part[512 + p]) + (part[1024 + p] + part[1536 + p]);
    part[p] = s * invl[p >> 7];
  }
  __syncthreads();
  {
    int e = tid & 127, jh = tid >> 7;
    float acc = jh ? 0.f : bvo[e];
    for (int h2 = 0; h2 < 4; ++h2) {
      const float* wv = Wvo + (size_t)(h2 * 128 + jh * 64) * 128 + e;
      const float* o = part + h2 * 128 + jh * 64;
#pragma unroll 4
      for (int j = 0; j < 64; ++j) acc += o[j] * wv[(size_t)j * 128];
    }
    red[tid] = acc;
  }
  __syncthreads();
  if (tid < 128) og[(b * 24 + t) * 128 + tid] = red[tid] + red[128 + tid];
}

// ---------------- K3: flash64 || patch ---------------------------------------

__global__ __launch_bounds__(256, 2) void k_big1(
    const float* __restrict__ gf, const u16* __restrict__ W1c_g,
    const float* __restrict__ gek_b1, const float* __restrict__ gev_b1,
    const u16* __restrict__ PkT_g, const float* __restrict__ ck_g,
    u16* __restrict__ accP_g, float* __restrict__ lP_g,
    const float* __restrict__ gridf, const u16* __restrict__ peB,
    u16* __restrict__ patchP) {
  __shared__ __align__(16) char smem[78336];
  int x = blockIdx.x;                   // 1280 blocks, 2:3 interleave
  int r5 = x % 5, q5 = x / 5;
  if (r5 < 2) {
    int fid = q5 * 2 + r5;              // 0..511
    flash_body<64, 1, false>(smem, gf, (const float*)nullptr, 0,
        W1c_g, gek_b1, gev_b1, PkT_g, ck_g, accP_g, lP_g,
        49152, 384, fid & 127, fid >> 7, 128);
  } else {
    int pid = q5 * 3 + (r5 - 2);        // 0..767
    patch_body(smem, pid % 96, pid / 96, gridf, peB, patchP);
  }
}

// ---------------- K4: ogred_graph || flash128 --------------------------------

__global__ __launch_bounds__(256, 2) void k_big2(
    const u16* __restrict__ accP_g, const float* __restrict__ lP_g,
    const float* __restrict__ Wvo_g, const float* __restrict__ bvo_g,
    float* __restrict__ og_g,
    const u16* __restrict__ patchP, const float* __restrict__ pe_b,
    const u16* __restrict__ W1c_r,
    const float* __restrict__ rk_b1, const float* __restrict__ rv_b1,
    const u16* __restrict__ PkT_r, const float* __restrict__ ck_r,
    u16* __restrict__ accP_r, float* __restrict__ lP_r) {
  __shared__ __align__(16) char smem[94720];
  int x = blockIdx.x;                   // 192 blocks
  int id = x >> 1;
  if (x & 1) {
    flash_body<128, 8, true>(smem, patchP, pe_b, 786432,
        W1c_r, rk_b1, rv_b1, PkT_r, ck_r, accP_r, lP_r,
        1536, 64, id % 24, id / 24, 24);
  } else {
    ogred_body(smem, id % 24, id / 24, 128, accP_g, lP_g, Wvo_g, bvo_g, og_g);
  }
}

// ---------------- K5: ogred_grid ---------------------------------------------

__global__ __launch_bounds__(256) void k_ogr(
    const u16* __restrict__ accP_r, const float* __restrict__ lP_r,
    const float* __restrict__ Wvo_r, const float* __restrict__ bvo_r,
    float* __restrict__ og_r) {
  __shared__ __align__(16) char smem[9232];
  int x = blockIdx.x;                   // 96 blocks
  ogred_body(smem, x % 24, x / 24, 24, accP_r, lP_r, Wvo_r, bvo_r, og_r);
}

// ---------------- K6: {upfuse (U-GEMM + up writer)} || {g_out writer} --------

__global__ __launch_bounds__(256) void k_writers(const float* __restrict__ og_r,
    const float* __restrict__ up_w, const float* __restrict__ up_b,
    float* __restrict__ outu,
    const float* __restrict__ og_g, float* __restrict__ outg) {
  __shared__ float og_s[24 * 128];      // 12 KB
  __shared__ float upw_s[128 * 64];     // 32 KB
  __shared__ float U_s[24 * 64];        // 6 KB
  int x = blockIdx.x;
  if (x < 512) {                        // ---- upfuse: block = (b, o)
    int b = x >> 7, o = x & 127;
    int tid = threadIdx.x;
    for (int i = tid; i < 24 * 128 / 4; i += 256)
      ((float4*)og_s)[i] = ((const float4*)(og_r + b * 3072))[i];
    for (int i = tid; i < 128 * 64 / 4; i += 256) {
      int c = i >> 4, pq4 = i & 15;
      ((float4*)upw_s)[i] = *(const float4*)(up_w + (size_t)c * 8192 + o * 64 + pq4 * 4);
    }
    __syncthreads();
    float bias = up_b[o];
    int pq = tid & 63, tg = tid >> 6;   // 4 groups x 6 tau
    float acc[6] = {0.f, 0.f, 0.f, 0.f, 0.f, 0.f};
    for (int c = 0; c < 128; c += 4) {
      float w0 = upw_s[c * 64 + pq], w1 = upw_s[(c + 1) * 64 + pq];
      float w2 = upw_s[(c + 2) * 64 + pq], w3 = upw_s[(c + 3) * 64 + pq];
#pragma unroll
      for (int r = 0; r < 6; ++r) {
        float4 g = *(const float4*)&og_s[(tg * 6 + r) * 128 + c];
        acc[r] += g.x * w0 + g.y * w1 + g.z * w2 + g.w * w3;
      }
    }
#pragma unroll
    for (int r = 0; r < 6; ++r) U_s[(tg * 6 + r) * 64 + pq] = acc[r] + bias;
    __syncthreads();
    for (int i4 = tid; i4 < 24 * 1024; i4 += 256) {
      int i = i4 * 4;                   // t*4096 + h*64 + w0
      int t = i >> 12, hw = i & 4095;
      int h = hw >> 6, w0 = hw & 63;
      int ii = h >> 3, p = h & 7, j = w0 >> 3, q0 = w0 & 7;
      int n = t * 64 + ii * 8 + j;
      float src = fmaxf((n + 0.5f) * (1.f / 64.f) - 0.5f, 0.f);
      int t0 = (int)src; float lam = src - (float)t0; int t1 = min(t0 + 1, 23);
      float4 a = *(const float4*)&U_s[t0 * 64 + p * 8 + q0];
      float4 c4 = *(const float4*)&U_s[t1 * 64 + p * 8 + q0];
      float4 r;
      r.x = a.x + lam * (c4.x - a.x); r.y = a.y + lam * (c4.y - a.y);
      r.z = a.z + lam * (c4.z - a.z); r.w = a.w + lam * (c4.w - a.w);
      *(float4*)&outu[((size_t)(b * 24 + t) * 128 + o) * 4096 + hw] = r;
    }
  } else {                              // ---- g_out lerp writer
    int vx = x - 512;                   // 0..4095
    int b = vx >> 10;
    const float* ogb = og_g + b * 3072;
    float* ob = outg + (size_t)b * 6291456;
    for (int i4 = (vx & 1023) * 256 + threadIdx.x; i4 < 1572864; i4 += 1024 * 256) {
      int i = i4 * 4;
      int n = i >> 7, e = i & 127;
      float src = fmaxf((n + 0.5f) * (1.f / 2048.f) - 0.5f, 0.f);
      int t0 = (int)src; float lam = src - (float)t0; int t1 = min(t0 + 1, 23);
      float4 a = *(const float4*)&ogb[t0 * 128 + e];
      float4 c = *(const float4*)&ogb[t1 * 128 + e];
      float4 o;
      o.x = a.x + lam * (c.x - a.x); o.y = a.y + lam * (c.y - a.y);
      o.z = a.z + lam * (c.z - a.z); o.w = a.w + lam * (c.w - a.w);
      *(float4*)&ob[i] = o;
    }
  }
}

// ---------------------------------------------------------------------------

extern "C" void kernel_launch(void* const* d_in, const int* in_sizes, int n_in,
                              void* d_out, int out_size, void* d_ws, size_t ws_size,
                              hipStream_t stream) {
  (void)in_sizes; (void)n_in; (void)out_size; (void)ws_size;
  const float* gf    = (const float*)d_in[0];
  const float* gridf = (const float*)d_in[1];
  const float* gti   = (const float*)d_in[2];
  const float* gek_w1 = (const float*)d_in[4],  *gek_b1 = (const float*)d_in[5];
  const float* gek_w2 = (const float*)d_in[6],  *gek_b2 = (const float*)d_in[7];
  const float* gev_w1 = (const float*)d_in[8],  *gev_b1 = (const float*)d_in[9];
  const float* gev_w2 = (const float*)d_in[10], *gev_b2 = (const float*)d_in[11];
  const float* rk_w1  = (const float*)d_in[12], *rk_b1  = (const float*)d_in[13];
  const float* rk_w2  = (const float*)d_in[14], *rk_b2  = (const float*)d_in[15];
  const float* rv_w1  = (const float*)d_in[16], *rv_b1  = (const float*)d_in[17];
  const float* rv_w2  = (const float*)d_in[18], *rv_b2  = (const float*)d_in[19];
  const float* te_w1  = (const float*)d_in[20], *te_b1  = (const float*)d_in[21];
  const float* te_w2  = (const float*)d_in[22], *te_b2  = (const float*)d_in[23];
  const float* pe_w   = (const float*)d_in[24], *pe_b   = (const float*)d_in[25];
  const float* up_w   = (const float*)d_in[26], *up_b   = (const float*)d_in[27];
  const float* ag_q_w = (const float*)d_in[28], *ag_q_b = (const float*)d_in[29];
  const float* ag_k_w = (const float*)d_in[30], *ag_k_b = (const float*)d_in[31];
  const float* ag_v_w = (const float*)d_in[32], *ag_v_b = (const float*)d_in[33];
  const float* ag_o_w = (const float*)d_in[34], *ag_o_b = (const float*)d_in[35];
  const float* ar_q_w = (const float*)d_in[36], *ar_q_b = (const float*)d_in[37];
  const float* ar_k_w = (const float*)d_in[38], *ar_k_b = (const float*)d_in[39];
  const float* ar_v_w = (const float*)d_in[40], *ar_v_b = (const float*)d_in[41];
  const float* ar_o_w = (const float*)d_in[42], *ar_o_b = (const float*)d_in[43];

  float* out = (float*)d_out;          // g_out (25165824 f) then up (50331648 f)
  float* ws = (float*)d_ws;
  size_t off = 0;
  auto A = [&](size_t n) { float* p = ws + off; off += n; return p; };
  float* q_g   = A(12288);   float* q_r   = A(12288);
  float* Wk_g  = A(16384);   float* bk_g  = A(128);
  float* Wv_g  = A(16384);   float* bv_g  = A(128);
  float* Wk_r  = A(16384);   float* bk_r  = A(128);
  float* Wv_r  = A(16384);   float* bv_r  = A(128);
  float* Wvo_g = A(65536);   float* bvo_g = A(128);
  float* Wvo_r = A(65536);   float* bvo_r = A(128);
  float* ck_g  = A(384);     float* ck_r  = A(384);
  u16*   PkT_g = (u16*)A(26112);   // 4*96*136 bf16
  u16*   PkT_r = (u16*)A(26112);
  u16*   W1c_g = (u16*)A(8192);    // 256*64 bf16
  u16*   W1c_r = (u16*)A(16384);   // 256*128 bf16
  u16*   peB   = (u16*)A(524288);  // 128*8192 bf16
  float* lP_g  = A(49152);   float* lP_r  = A(9216);
  float* og_g  = A(12288);   float* og_r  = A(12288);
  u16*   accP_g = (u16*)A(3145728);   // 4*128*12288 bf16
  u16*   patchP = (u16*)A(3145728);   // 8*6144*128 bf16
  u16*   accP_r = (u16*)A(589824);    // 4*24*12288 bf16

  k_pre1<<<2148, 128, 0, stream>>>(
      gek_w1, gev_w1, rk_w1, rv_w1, W1c_g, W1c_r,
      pe_w, peB,
      gti, te_w1, te_b1, te_w2, te_b2, ag_q_w, ag_q_b, ar_q_w, ar_q_b, q_g, q_r,
      gek_w2, gek_b2, ag_k_w, ag_k_b, Wk_g, bk_g,
      gev_w2, gev_b2, ag_v_w, ag_v_b, Wv_g, bv_g,
      rk_w2,  rk_b2,  ar_k_w, ar_k_b, Wk_r, bk_r,
      rv_w2,  rv_b2,  ar_v_w, ar_v_b, Wv_r, bv_r);
  k_wvopk<<<dim3(129, 16), 128, 0, stream>>>(
      Wv_g, bv_g, ag_o_w, ag_o_b, Wvo_g, bvo_g,
      Wv_r, bv_r, ar_o_w, ar_o_b, Wvo_r, bvo_r,
      Wk_g, bk_g, q_g, PkT_g, ck_g,
      Wk_r, bk_r, q_r, PkT_r, ck_r);

  // K3: graph flash (512 virtual blocks) || patch conv (768 virtual blocks)
  k_big1<<<1280, 256, 0, stream>>>(
      gf, W1c_g, gek_b1, gev_b1, PkT_g, ck_g, accP_g, lP_g,
      gridf, peB, patchP);
  // K4: graph chunk-reduce+og (96) || grid flash (96)
  k_big2<<<192, 256, 0, stream>>>(
      accP_g, lP_g, Wvo_g, bvo_g, og_g,
      patchP, pe_b, W1c_r, rk_b1, rv_b1, PkT_r, ck_r, accP_r, lP_r);
  // K5: grid chunk-reduce+og (96)
  k_ogr<<<96, 256, 0, stream>>>(accP_r, lP_r, Wvo_r, bvo_r, og_r);
  // K6: up writer (512) || g_out writer (4096)
  k_writers<<<4608, 256, 0, stream>>>(og_r, up_w, up_b, out + 25165824, og_g, out);
}

// Round 8
// 206.213 us; speedup vs baseline: 2.3436x; 1.0351x over previous
//
#include <hip/hip_runtime.h>

// ---------------------------------------------------------------------------
// GraphGridCrossAttnModel — round 8: amortization pass.
//   K1 pre1 | K2 wvopk | K3 {flash64(32ch x 24 tiles) || patch}
//   K4 {ogred_g || flash128(8ch x 3 tiles)} | K5 {ogred_r || gout} | K6 upfuse
// MFMA layout (16x16x32 bf16, m89-verified):
//  A: m=l&15, k=(l>>4)*8+j ; B: n=l&15, k=(l>>4)*8+j ; D: col=l&15, row=(l>>4)*4+reg
// ---------------------------------------------------------------------------

typedef unsigned short u16;
using bf8 = __attribute__((ext_vector_type(8))) short;
using f4v = __attribute__((ext_vector_type(4))) float;
#define MFMA16(a, b, c) __builtin_amdgcn_mfma_f32_16x16x32_bf16(a, b, c, 0, 0, 0)

constexpr float INV_SCALE = 0.17677669529663687f;   // 1/sqrt(32)

__device__ __forceinline__ u16 f2bf(float f) {
  unsigned u = __float_as_uint(f);
  u += 0x7FFFu + ((u >> 16) & 1u);
  return (u16)(u >> 16);
}
__device__ __forceinline__ unsigned pk2(float a, float b) {
  return (unsigned)f2bf(a) | ((unsigned)f2bf(b) << 16);
}
__device__ __forceinline__ float bflo(unsigned v) { return __uint_as_float(v << 16); }
__device__ __forceinline__ float bfhi(unsigned v) { return __uint_as_float(v & 0xffff0000u); }

// ---------------- K1: fused precompute: w1c | cvt | teq | fold ---------------

__global__ __launch_bounds__(128) void k_pre1(
    const float* gk_w1, const float* gv_w1, const float* rk_w1, const float* rv_w1,
    u16* W1c_g, u16* W1c_r,
    const float* pe_w, u16* peB,
    const float* tidx, const float* te_w1, const float* te_b1,
    const float* te_w2, const float* te_b2,
    const float* wg, const float* bg, const float* wr, const float* br,
    float* qg, float* qr,
    const float* A0, const float* Ab0, const float* B0, const float* Bb0, float* O0, float* Ob0,
    const float* A1, const float* Ab1, const float* B1, const float* Bb1, float* O1, float* Ob1,
    const float* A2, const float* Ab2, const float* B2, const float* Bb2, float* O2, float* Ob2,
    const float* A3, const float* Ab3, const float* B3, const float* Bb3, float* O3, float* Ob3) {
  int x = blockIdx.x, e = threadIdx.x;
  __shared__ float sh[256];
  if (x < 512) {                    // --- W1c bf16 transpose-pack
    int c = x & 255, brn = x >> 8;
    int DIN = brn ? 128 : 64;
    if (e < DIN) {
      const float* src = brn ? (c < 128 ? rk_w1 : rv_w1) : (c < 128 ? gk_w1 : gv_w1);
      u16* dst = brn ? W1c_r : W1c_g;
      dst[c * DIN + e] = f2bf(src[e * 128 + (c & 127)]);
    }
  } else if (x < 1536) {            // --- pe_w -> bf16
    int i = ((x - 512) * 128 + e) * 8;
    float4 v0 = *(const float4*)(pe_w + i);
    float4 v1 = *(const float4*)(pe_w + i + 4);
    uint4 o; o.x = pk2(v0.x, v0.y); o.y = pk2(v0.z, v0.w);
    o.z = pk2(v1.x, v1.y); o.w = pk2(v1.z, v1.w);
    *(uint4*)&peB[i] = o;
  } else if (x < 1632) {            // --- te -> q_g/q_r
    int row = x - 1536;
    float tv = tidx[row];
    sh[e] = fmaxf(tv * te_w1[e] + te_b1[e], 0.f);
    __syncthreads();
    float a = te_b2[e];
    for (int j = 0; j < 128; ++j) a += sh[j] * te_w2[j * 128 + e];
    sh[128 + e] = a;
    __syncthreads();
    float ag = bg[e], ar = br[e];
    for (int j = 0; j < 128; ++j) {
      float xx = sh[128 + j];
      ag += xx * wg[j * 128 + e];
      ar += xx * wr[j * 128 + e];
    }
    qg[row * 128 + e] = ag;
    qr[row * 128 + e] = ar;
  } else {                          // --- fold W2@Wqkv
    int sub = x - 1632;
    int task = sub / 129, j = sub % 129;
    const float *A, *Ab, *Bm, *Bb; float *O, *Ob;
    switch (task) {
      case 0: A=A0; Ab=Ab0; Bm=B0; Bb=Bb0; O=O0; Ob=Ob0; break;
      case 1: A=A1; Ab=Ab1; Bm=B1; Bb=Bb1; O=O1; Ob=Ob1; break;
      case 2: A=A2; Ab=Ab2; Bm=B2; Bb=Bb2; O=O2; Ob=Ob2; break;
      default:A=A3; Ab=Ab3; Bm=B3; Bb=Bb3; O=O3; Ob=Ob3; break;
    }
    sh[e] = (j < 128) ? A[j * 128 + e] : Ab[e];
    __syncthreads();
    float acc = (j < 128) ? 0.f : Bb[e];
    for (int m = 0; m < 128; ++m) acc += sh[m] * Bm[m * 128 + e];
    if (j < 128) O[j * 128 + e] = acc; else Ob[e] = acc;
  }
}

// ---------------- K2: merged Wvo/bvo + PkT/ck --------------------------------

__global__ __launch_bounds__(128) void k_wvopk(
    const float* Wv_g, const float* bv_g, const float* ow_g, const float* ob_g, float* Wvo_g, float* bvo_g,
    const float* Wv_r, const float* bv_r, const float* ow_r, const float* ob_r, float* Wvo_r, float* bvo_r,
    const float* Wk_g, const float* bk_g, const float* q_g, u16* PkT_g, float* ck_g,
    const float* Wk_r, const float* bk_r, const float* q_r, u16* PkT_r, float* ck_r) {
  int j = blockIdx.x, e = threadIdx.x;
  if (blockIdx.y < 8) {
    int br = blockIdx.y >> 2, h = blockIdx.y & 3;
    const float* Wv = br ? Wv_r : Wv_g;  const float* bv = br ? bv_r : bv_g;
    const float* ow = br ? ow_r : ow_g;  const float* ob = br ? ob_r : ob_g;
    float* Wvo = br ? Wvo_r : Wvo_g;     float* bvo = br ? bvo_r : bvo_g;
    if (j < 128) {
      __shared__ float wrow[32];
      if (e < 32) wrow[e] = Wv[j * 128 + h * 32 + e];
      __syncthreads();
      float acc = 0.f;
      for (int d = 0; d < 32; ++d) acc += wrow[d] * ow[(h * 32 + d) * 128 + e];
      Wvo[(h * 128 + j) * 128 + e] = acc;
    } else if (h == 0) {
      __shared__ float bbv[128];
      bbv[e] = bv[e];
      __syncthreads();
      float acc = ob[e];
      for (int m = 0; m < 128; ++m) acc += bbv[m] * ow[m * 128 + e];
      bvo[e] = acc;
    }
  } else {
    int y = blockIdx.y - 8;
    int br = y >> 2, b = y & 3;
    int hq = e;
    if (hq >= 96) return;
    const float* Wk = br ? Wk_r : Wk_g;  const float* bk = br ? bk_r : bk_g;
    const float* q  = br ? q_r  : q_g;
    u16* PkT = br ? PkT_r : PkT_g;       float* ck = br ? ck_r : ck_g;
    int h = hq / 24, t = hq % 24;
    const float* qrow = q + (b * 24 + t) * 128 + h * 32;
    if (j < 128) {
      const float* wrow = Wk + j * 128 + h * 32;
      float acc = 0.f;
      for (int d = 0; d < 32; ++d) acc += wrow[d] * qrow[d];
      PkT[((size_t)b * 96 + hq) * 136 + j] = f2bf(acc * INV_SCALE);
    } else {
      float acc = 0.f;
      for (int d = 0; d < 32; ++d) acc += bk[h * 32 + d] * qrow[d];
      ck[b * 96 + hq] = acc * INV_SCALE;
    }
  }
}

// ---------------- flash body (device fn, LDS carved from smem) ---------------
// 4 waves; 64-key tiles; Xt double-buffered; 3 barriers/tile.

template <int DIN, int NRED, bool INBF>
__device__ __forceinline__ void flash_body(char* smem,
    const void* __restrict__ Xv, const float* __restrict__ redbias, size_t rstride,
    const u16* __restrict__ W1c, const float* __restrict__ b1k, const float* __restrict__ b1v,
    const u16* __restrict__ PkT, const float* __restrict__ ck,
    u16* __restrict__ accP, float* __restrict__ lP,
    int KL, int kpb, int chunk, int b, int nchunk) {
  constexpr int KS = DIN / 32;
  constexpr int PD = DIN + 8;
  constexpr int PH = 136, PV = 72, PP = 72;
  constexpr int NR = DIN / 16;
  constexpr int XTN = 64 * PD;                  // u16 per Xt buffer
  u16* Xt   = (u16*)smem;                       // [2][XTN]
  u16* HB   = (u16*)(smem + 4 * XTN);           // 9216 u16
  u16* Pt   = (u16*)(smem + 4 * XTN + 18432);   // 96*72
  u16* Pk_s = (u16*)(smem + 4 * XTN + 18432 + 13824);   // 96*136
  float* lred = (float*)(smem + 4 * XTN + 18432 + 13824 + 26112);  // 384 f

  int t = threadIdx.x;
  int l = t & 63, w = t >> 6;
  int l16 = l & 15, l4 = l >> 4;

  size_t xbase = (size_t)b * KL * DIN + (size_t)chunk * kpb * DIN;

  // stage PkT[b] into LDS (once per block)
  {
    const unsigned* ps = (const unsigned*)(PkT + (size_t)b * 96 * 136);
    unsigned* pd = (unsigned*)Pk_s;
    for (int i = t; i < 96 * 136 / 2; i += 256) pd[i] = ps[i];
  }

  bf8 wkA[2][KS], wvB[2][KS];
#pragma unroll
  for (int m = 0; m < 2; ++m)
#pragma unroll
    for (int ks = 0; ks < KS; ++ks) {
      int hid = w * 32 + m * 16 + l16;
      wkA[m][ks] = *(const bf8*)(W1c + (size_t)hid * DIN + ks * 32 + l4 * 8);
      wvB[m][ks] = *(const bf8*)(W1c + (size_t)(128 + hid) * DIN + ks * 32 + l4 * 8);
    }
  float bkA[2][4], bvB[2], ckr[6];
#pragma unroll
  for (int m = 0; m < 2; ++m)
#pragma unroll
    for (int r = 0; r < 4; ++r) bkA[m][r] = b1k[w * 32 + m * 16 + l4 * 4 + r];
#pragma unroll
  for (int n = 0; n < 2; ++n) bvB[n] = b1v[w * 32 + n * 16 + l16];
#pragma unroll
  for (int n = 0; n < 6; ++n) ckr[n] = ck[b * 96 + n * 16 + l16];

  f4v accO[6][2];
#pragma unroll
  for (int m = 0; m < 6; ++m)
#pragma unroll
    for (int n = 0; n < 2; ++n) accO[m][n] = (f4v){0.f, 0.f, 0.f, 0.f};
  float lacc[6] = {0.f, 0.f, 0.f, 0.f, 0.f, 0.f};

  float4 xr[NR];
  auto load_tile = [&](int kt) {
#pragma unroll
    for (int r = 0; r < NR; ++r) {
      int idx = (r * 256 + t) * 4;
      if constexpr (!INBF) {
        const float* Xrow = (const float*)Xv + xbase + (size_t)kt * 64 * DIN;
        xr[r] = *(const float4*)(Xrow + idx);
      } else {
        const u16* Xrow = (const u16*)Xv + xbase + (size_t)kt * 64 * DIN;
        int din = idx % DIN;
        float4 a = *(const float4*)(redbias + din);
#pragma unroll
        for (int c = 0; c < NRED; ++c) {
          uint2 v = *(const uint2*)(Xrow + (size_t)c * rstride + idx);
          a.x += bflo(v.x); a.y += bfhi(v.x);
          a.z += bflo(v.y); a.w += bfhi(v.y);
        }
        xr[r] = a;
      }
    }
  };

  int ntile = kpb >> 6;
  load_tile(0);
  int buf = 0;
  for (int kt = 0; kt < ntile; ++kt) {
    // ---- write staged tile (regs -> LDS bf16), prefetch next ----
#pragma unroll
    for (int r = 0; r < NR; ++r) {
      int idx = (r * 256 + t) * 4;
      int key = idx / DIN, din = idx % DIN;
      uint2 o; o.x = pk2(xr[r].x, xr[r].y); o.y = pk2(xr[r].z, xr[r].w);
      *(uint2*)&Xt[buf * XTN + key * PD + din] = o;
    }
    if (kt + 1 < ntile) load_tile(kt + 1);
    __syncthreads();                                   // b1 (Xt ready; HB free)

    // ---- G1a: Hk = W1k^T @ X^T ----
    {
      f4v hk[2][4];
#pragma unroll
      for (int m = 0; m < 2; ++m)
#pragma unroll
        for (int n = 0; n < 4; ++n) hk[m][n] = (f4v){0.f, 0.f, 0.f, 0.f};
#pragma unroll
      for (int ks = 0; ks < KS; ++ks) {
        bf8 xf[4];
#pragma unroll
        for (int n = 0; n < 4; ++n)
          xf[n] = *(const bf8*)&Xt[buf * XTN + (n * 16 + l16) * PD + ks * 32 + l4 * 8];
#pragma unroll
        for (int m = 0; m < 2; ++m)
#pragma unroll
          for (int n = 0; n < 4; ++n) hk[m][n] = MFMA16(wkA[m][ks], xf[n], hk[m][n]);
      }
#pragma unroll
      for (int m = 0; m < 2; ++m)
#pragma unroll
        for (int n = 0; n < 4; ++n) {
          int key = n * 16 + l16;
          int hid0 = w * 32 + m * 16 + l4 * 4;
          float v0 = fmaxf(hk[m][n][0] + bkA[m][0], 0.f);
          float v1 = fmaxf(hk[m][n][1] + bkA[m][1], 0.f);
          float v2 = fmaxf(hk[m][n][2] + bkA[m][2], 0.f);
          float v3 = fmaxf(hk[m][n][3] + bkA[m][3], 0.f);
          uint2 o; o.x = pk2(v0, v1); o.y = pk2(v2, v3);
          *(uint2*)&HB[key * PH + hid0] = o;
        }
    }
    __syncthreads();                                   // b2 (Hk ready)

    // ---- G2: S = Hk @ Pk ----
    {
      f4v sa[6];
#pragma unroll
      for (int n = 0; n < 6; ++n) sa[n] = (f4v){ckr[n], ckr[n], ckr[n], ckr[n]};
#pragma unroll
      for (int ks = 0; ks < 4; ++ks) {
        bf8 a = *(const bf8*)&HB[(w * 16 + l16) * PH + ks * 32 + l4 * 8];
#pragma unroll
        for (int n = 0; n < 6; ++n) {
          bf8 bp = *(const bf8*)&Pk_s[(n * 16 + l16) * 136 + ks * 32 + l4 * 8];
          sa[n] = MFMA16(a, bp, sa[n]);
        }
      }
#pragma unroll
      for (int n = 0; n < 6; ++n) {
        float e0 = __expf(sa[n][0]), e1 = __expf(sa[n][1]);
        float e2 = __expf(sa[n][2]), e3 = __expf(sa[n][3]);
        float ls = (e0 + e1) + (e2 + e3);
        ls += __shfl_xor(ls, 16);
        ls += __shfl_xor(ls, 32);
        lacc[n] += ls;
        uint2 o; o.x = pk2(e0, e1); o.y = pk2(e2, e3);
        *(uint2*)&Pt[(n * 16 + l16) * PP + w * 16 + l4 * 4] = o;
      }
    }
    __syncthreads();                                   // b3 (Pt ready; HB-k readers done)

    // ---- G1b: Hv = X @ W1v -> HvT[hid][key] (own-wave rows) ----
    {
      f4v hv[4][2];
#pragma unroll
      for (int m = 0; m < 4; ++m)
#pragma unroll
        for (int n = 0; n < 2; ++n) hv[m][n] = (f4v){0.f, 0.f, 0.f, 0.f};
#pragma unroll
      for (int ks = 0; ks < KS; ++ks) {
        bf8 xa[4];
#pragma unroll
        for (int m = 0; m < 4; ++m)
          xa[m] = *(const bf8*)&Xt[buf * XTN + (m * 16 + l16) * PD + ks * 32 + l4 * 8];
#pragma unroll
        for (int m = 0; m < 4; ++m)
#pragma unroll
          for (int n = 0; n < 2; ++n) hv[m][n] = MFMA16(xa[m], wvB[n][ks], hv[m][n]);
      }
#pragma unroll
      for (int m = 0; m < 4; ++m)
#pragma unroll
        for (int n = 0; n < 2; ++n) {
          int d = w * 32 + n * 16 + l16;
          int key0 = m * 16 + l4 * 4;
          float v0 = fmaxf(hv[m][n][0] + bvB[n], 0.f);
          float v1 = fmaxf(hv[m][n][1] + bvB[n], 0.f);
          float v2 = fmaxf(hv[m][n][2] + bvB[n], 0.f);
          float v3 = fmaxf(hv[m][n][3] + bvB[n], 0.f);
          uint2 o; o.x = pk2(v0, v1); o.y = pk2(v2, v3);
          *(uint2*)&HB[d * PV + key0] = o;
        }
    }
    // NO barrier: G3 reads only rows w*32..w*32+31 of HvT, written by this
    // same wave; DS ops are in-order per wave. Cross-wave HB reuse is guarded
    // by next iteration's b1.

    // ---- G3: ACC += P^T @ Hv ----
#pragma unroll
    for (int ks = 0; ks < 2; ++ks) {
      bf8 pa[6];
#pragma unroll
      for (int m = 0; m < 6; ++m)
        pa[m] = *(const bf8*)&Pt[(m * 16 + l16) * PP + ks * 32 + l4 * 8];
#pragma unroll
      for (int n = 0; n < 2; ++n) {
        bf8 hb = *(const bf8*)&HB[(w * 32 + n * 16 + l16) * PV + ks * 32 + l4 * 8];
#pragma unroll
        for (int m = 0; m < 6; ++m) accO[m][n] = MFMA16(pa[m], hb, accO[m][n]);
      }
    }
    buf ^= 1;
  }

  // ---- write partial ACC (96x128 bf16) and partial l (96 fp32) ----
  u16* ap = accP + (size_t)(b * nchunk + chunk) * 96 * 128;
#pragma unroll
  for (int m = 0; m < 6; ++m)
#pragma unroll
    for (int n = 0; n < 2; ++n) {
      int d = w * 32 + n * 16 + l16;
#pragma unroll
      for (int r = 0; r < 4; ++r) {
        int hq = m * 16 + l4 * 4 + r;
        ap[hq * 128 + d] = f2bf(accO[m][n][r]);
      }
    }
  if (l4 == 0) {
#pragma unroll
    for (int n = 0; n < 6; ++n) lred[w * 96 + n * 16 + l16] = lacc[n];
  }
  __syncthreads();
  if (t < 96) {
    float s = lred[t] + lred[96 + t] + lred[192 + t] + lred[288 + t];
    lP[(size_t)(b * nchunk + chunk) * 96 + t] = s;
  }
}

// ---------------- patch body (device fn) -------------------------------------

__device__ __forceinline__ void patch_body(char* smem, int bt, int kc,
    const float* __restrict__ X, const u16* __restrict__ peB,
    u16* __restrict__ patchP) {
  u16* Xp = (u16*)smem;                 // 64*136
  u16* Wt = (u16*)(smem + 17408);       // 128*128, XOR-swizzled slot ^= co&7
  int t = threadIdx.x;
  int l = t & 63, w = t >> 6;
  int l16 = l & 15, l4 = l >> 4;
  const float* Xbt = X + (size_t)bt * 524288 + (size_t)kc * 65536;

  f4v acc[4][2];
#pragma unroll
  for (int m = 0; m < 4; ++m)
#pragma unroll
    for (int n = 0; n < 2; ++n) acc[m][n] = (f4v){0.f, 0.f, 0.f, 0.f};

  float4 xr[8];
  auto loadX = [&](int s) {
    const float* img = Xbt + (size_t)s * 8192;
#pragma unroll
    for (int r = 0; r < 8; ++r) xr[r] = *(const float4*)(img + (r * 256 + t) * 4);
  };
  loadX(0);

  for (int s = 0; s < 8; ++s) {
#pragma unroll
    for (int r = 0; r < 8; ++r) {
      int idx = (r * 256 + t) * 4;
      int cl = idx >> 12, off = idx & 4095;
      int h = off >> 6, w0 = off & 63;
      int patch = (h >> 3) * 8 + (w0 >> 3);
      int within = (h & 7) * 8 + (w0 & 7);
      uint2 o; o.x = pk2(xr[r].x, xr[r].y); o.y = pk2(xr[r].z, xr[r].w);
      *(uint2*)&Xp[patch * 136 + cl * 64 + within] = o;
    }
    {
      int colbase = kc * 1024 + s * 128;
#pragma unroll
      for (int r = 0; r < 8; ++r) {
        int idx = r * 256 + t;
        int co = idx >> 4, part = idx & 15;
        int slot = part ^ (co & 7);
        uint4 v = *(const uint4*)(peB + (size_t)co * 8192 + colbase + part * 8);
        *(uint4*)&Wt[co * 128 + slot * 8] = v;
      }
    }
    if (s < 7) loadX(s + 1);
    __syncthreads();
#pragma unroll
    for (int ks2 = 0; ks2 < 4; ++ks2) {
      bf8 af[4];
#pragma unroll
      for (int m = 0; m < 4; ++m)
        af[m] = *(const bf8*)&Xp[(m * 16 + l16) * 136 + ks2 * 32 + l4 * 8];
#pragma unroll
      for (int n = 0; n < 2; ++n) {
        int co = w * 32 + n * 16 + l16;
        int slot = (ks2 * 4 + l4) ^ (co & 7);
        bf8 bf_ = *(const bf8*)&Wt[co * 128 + slot * 8];
#pragma unroll
        for (int m = 0; m < 4; ++m) acc[m][n] = MFMA16(af[m], bf_, acc[m][n]);
      }
    }
    __syncthreads();
  }
  u16* outp = patchP + ((size_t)kc * 6144 + bt * 64) * 128;
#pragma unroll
  for (int m = 0; m < 4; ++m)
#pragma unroll
    for (int n = 0; n < 2; ++n) {
      int d = w * 32 + n * 16 + l16;
#pragma unroll
      for (int r = 0; r < 4; ++r) {
        int patch = m * 16 + l4 * 4 + r;
        outp[patch * 128 + d] = f2bf(acc[m][n][r]);
      }
    }
}

// ---------------- ogred body (vectorized) ------------------------------------
// thread = (cq[4] x h[4] x oct[16]); uint4 loads (8 bf16); full-block GEMM.

__device__ __forceinline__ void ogred_body(char* smem, int t, int b, int nc,
    const u16* __restrict__ accP, const float* __restrict__ lP,
    const float* __restrict__ Wvo, const float* __restrict__ bvo,
    float* __restrict__ og) {
  float* part = (float*)smem;            // 2048 f
  float* invl = part + 2048;             // 4 f
  float* red  = part + 2052;             // 256 f
  int tid = threadIdx.x;
  int oct = tid & 15, h = (tid >> 4) & 3, cq = tid >> 6;
  int cn = nc >> 2;
  float a8[8];
#pragma unroll
  for (int k = 0; k < 8; ++k) a8[k] = 0.f;
  const u16* base = accP + ((size_t)(b * nc + cq * cn) * 96 + h * 24 + t) * 128 + oct * 8;
  for (int c = 0; c < cn; ++c) {
    uint4 v = *(const uint4*)(base + (size_t)c * 12288);
    a8[0] += bflo(v.x); a8[1] += bfhi(v.x);
    a8[2] += bflo(v.y); a8[3] += bfhi(v.y);
    a8[4] += bflo(v.z); a8[5] += bfhi(v.z);
    a8[6] += bflo(v.w); a8[7] += bfhi(v.w);
  }
#pragma unroll
  for (int k = 0; k < 8; ++k) part[cq * 512 + h * 128 + oct * 8 + k] = a8[k];
  if (tid < 64) {                        // l-sum: one wave, 16 lanes per head
    int hh = tid >> 4, c0 = tid & 15;
    float ls = 0.f;
    for (int c = c0; c < nc; c += 16) ls += lP[(size_t)(b * nc + c) * 96 + hh * 24 + t];
    ls += __shfl_xor(ls, 8); ls += __shfl_xor(ls, 4);
    ls += __shfl_xor(ls, 2); ls += __shfl_xor(ls, 1);
    if (c0 == 0) invl[hh] = 1.f / ls;
  }
  __syncthreads();
  for (int p = tid; p < 512; p += 256) {
    float s = (part[p] + part[512 + p]) + (part[1024 + p] + part[1536 + p]);
    part[p] = s * invl[p >> 7];
  }
  __syncthreads();
  {
    int e = tid & 127, jh = tid >> 7;
    float acc = jh ? 0.f : bvo[e];
    for (int h2 = 0; h2 < 4; ++h2) {
      const float* wv = Wvo + (size_t)(h2 * 128 + jh * 64) * 128 + e;
      const float* o = part + h2 * 128 + jh * 64;
#pragma unroll 4
      for (int j = 0; j < 64; ++j) acc += o[j] * wv[(size_t)j * 128];
    }
    red[tid] = acc;
  }
  __syncthreads();
  if (tid < 128) og[(b * 24 + t) * 128 + tid] = red[tid] + red[128 + tid];
}

// ---------------- K3: flash64 (128 blocks, 24 tiles) || patch (768) ----------

__global__ __launch_bounds__(256, 2) void k_big1(
    const float* __restrict__ gf, const u16* __restrict__ W1c_g,
    const float* __restrict__ gek_b1, const float* __restrict__ gev_b1,
    const u16* __restrict__ PkT_g, const float* __restrict__ ck_g,
    u16* __restrict__ accP_g, float* __restrict__ lP_g,
    const float* __restrict__ gridf, const u16* __restrict__ peB,
    u16* __restrict__ patchP) {
  __shared__ __align__(16) char smem[78336];
  int x = blockIdx.x;                   // 896 blocks: flash first (long-running)
  if (x < 128) {
    flash_body<64, 1, false>(smem, gf, (const float*)nullptr, 0,
        W1c_g, gek_b1, gev_b1, PkT_g, ck_g, accP_g, lP_g,
        49152, 1536, x & 31, x >> 5, 32);
  } else {
    int pid = x - 128;                  // 0..767
    patch_body(smem, pid % 96, pid / 96, gridf, peB, patchP);
  }
}

// ---------------- K4: ogred_graph (96) || flash128 (32 blocks, 3 tiles) ------

__global__ __launch_bounds__(256, 2) void k_big2(
    const u16* __restrict__ accP_g, const float* __restrict__ lP_g,
    const float* __restrict__ Wvo_g, const float* __restrict__ bvo_g,
    float* __restrict__ og_g,
    const u16* __restrict__ patchP, const float* __restrict__ pe_b,
    const u16* __restrict__ W1c_r,
    const float* __restrict__ rk_b1, const float* __restrict__ rv_b1,
    const u16* __restrict__ PkT_r, const float* __restrict__ ck_r,
    u16* __restrict__ accP_r, float* __restrict__ lP_r) {
  __shared__ __align__(16) char smem[94720];
  int x = blockIdx.x;                   // 128 blocks
  if (x < 96) {
    ogred_body(smem, x % 24, x / 24, 32, accP_g, lP_g, Wvo_g, bvo_g, og_g);
  } else {
    int fid = x - 96;                   // 0..31: 8 chunks x 4 batches
    flash_body<128, 8, true>(smem, patchP, pe_b, 786432,
        W1c_r, rk_b1, rv_b1, PkT_r, ck_r, accP_r, lP_r,
        1536, 192, fid & 7, fid >> 3, 8);
  }
}

// ---------------- K5: ogred_grid (96) || g_out writer (4096) -----------------

__global__ __launch_bounds__(256) void k_big3(
    const u16* __restrict__ accP_r, const float* __restrict__ lP_r,
    const float* __restrict__ Wvo_r, const float* __restrict__ bvo_r,
    float* __restrict__ og_r,
    const float* __restrict__ og_g, float* __restrict__ outg) {
  __shared__ __align__(16) char smem[9232];
  int x = blockIdx.x;                   // 96 + 4096 blocks
  if (x < 96) {
    ogred_body(smem, x % 24, x / 24, 8, accP_r, lP_r, Wvo_r, bvo_r, og_r);
  } else {
    int vx = x - 96;
    int b = vx >> 10;
    const float* ogb = og_g + b * 3072;
    float* ob = outg + (size_t)b * 6291456;
    for (int i4 = (vx & 1023) * 256 + threadIdx.x; i4 < 1572864; i4 += 1024 * 256) {
      int i = i4 * 4;
      int n = i >> 7, e = i & 127;
      float src = fmaxf((n + 0.5f) * (1.f / 2048.f) - 0.5f, 0.f);
      int t0 = (int)src; float lam = src - (float)t0; int t1 = min(t0 + 1, 23);
      float4 a = *(const float4*)&ogb[t0 * 128 + e];
      float4 c = *(const float4*)&ogb[t1 * 128 + e];
      float4 o;
      o.x = a.x + lam * (c.x - a.x); o.y = a.y + lam * (c.y - a.y);
      o.z = a.z + lam * (c.z - a.z); o.w = a.w + lam * (c.w - a.w);
      *(float4*)&ob[i] = o;
    }
  }
}

// ---------------- K6: upfuse (U-GEMM + up lerp-upsample writer) --------------

__global__ __launch_bounds__(256) void k_upfuse(const float* __restrict__ og_r,
    const float* __restrict__ up_w, const float* __restrict__ up_b,
    float* __restrict__ outu) {
  int b = blockIdx.x >> 7, o = blockIdx.x & 127;
  __shared__ float og_s[24 * 128];      // 12 KB
  __shared__ float upw_s[128 * 64];     // 32 KB
  __shared__ float U_s[24 * 64];        // 6 KB
  int tid = threadIdx.x;
  for (int i = tid; i < 24 * 128 / 4; i += 256)
    ((float4*)og_s)[i] = ((const float4*)(og_r + b * 3072))[i];
  for (int i = tid; i < 128 * 64 / 4; i += 256) {
    int c = i >> 4, pq4 = i & 15;
    ((float4*)upw_s)[i] = *(const float4*)(up_w + (size_t)c * 8192 + o * 64 + pq4 * 4);
  }
  __syncthreads();
  float bias = up_b[o];
  int pq = tid & 63, tg = tid >> 6;     // 4 groups x 6 tau
  float acc[6] = {0.f, 0.f, 0.f, 0.f, 0.f, 0.f};
  for (int c = 0; c < 128; c += 4) {
    float w0 = upw_s[c * 64 + pq], w1 = upw_s[(c + 1) * 64 + pq];
    float w2 = upw_s[(c + 2) * 64 + pq], w3 = upw_s[(c + 3) * 64 + pq];
#pragma unroll
    for (int r = 0; r < 6; ++r) {
      float4 g = *(const float4*)&og_s[(tg * 6 + r) * 128 + c];
      acc[r] += g.x * w0 + g.y * w1 + g.z * w2 + g.w * w3;
    }
  }
#pragma unroll
  for (int r = 0; r < 6; ++r) U_s[(tg * 6 + r) * 64 + pq] = acc[r] + bias;
  __syncthreads();
  for (int i4 = tid; i4 < 24 * 1024; i4 += 256) {
    int i = i4 * 4;                     // t*4096 + h*64 + w0
    int t = i >> 12, hw = i & 4095;
    int h = hw >> 6, w0 = hw & 63;
    int ii = h >> 3, p = h & 7, j = w0 >> 3, q0 = w0 & 7;
    int n = t * 64 + ii * 8 + j;
    float src = fmaxf((n + 0.5f) * (1.f / 64.f) - 0.5f, 0.f);
    int t0 = (int)src; float lam = src - (float)t0; int t1 = min(t0 + 1, 23);
    float4 a = *(const float4*)&U_s[t0 * 64 + p * 8 + q0];
    float4 c4 = *(const float4*)&U_s[t1 * 64 + p * 8 + q0];
    float4 r;
    r.x = a.x + lam * (c4.x - a.x); r.y = a.y + lam * (c4.y - a.y);
    r.z = a.z + lam * (c4.z - a.z); r.w = a.w + lam * (c4.w - a.w);
    *(float4*)&outu[((size_t)(b * 24 + t) * 128 + o) * 4096 + hw] = r;
  }
}

// ---------------------------------------------------------------------------

extern "C" void kernel_launch(void* const* d_in, const int* in_sizes, int n_in,
                              void* d_out, int out_size, void* d_ws, size_t ws_size,
                              hipStream_t stream) {
  (void)in_sizes; (void)n_in; (void)out_size; (void)ws_size;
  const float* gf    = (const float*)d_in[0];
  const float* gridf = (const float*)d_in[1];
  const float* gti   = (const float*)d_in[2];
  const float* gek_w1 = (const float*)d_in[4],  *gek_b1 = (const float*)d_in[5];
  const float* gek_w2 = (const float*)d_in[6],  *gek_b2 = (const float*)d_in[7];
  const float* gev_w1 = (const float*)d_in[8],  *gev_b1 = (const float*)d_in[9];
  const float* gev_w2 = (const float*)d_in[10], *gev_b2 = (const float*)d_in[11];
  const float* rk_w1  = (const float*)d_in[12], *rk_b1  = (const float*)d_in[13];
  const float* rk_w2  = (const float*)d_in[14], *rk_b2  = (const float*)d_in[15];
  const float* rv_w1  = (const float*)d_in[16], *rv_b1  = (const float*)d_in[17];
  const float* rv_w2  = (const float*)d_in[18], *rv_b2  = (const float*)d_in[19];
  const float* te_w1  = (const float*)d_in[20], *te_b1  = (const float*)d_in[21];
  const float* te_w2  = (const float*)d_in[22], *te_b2  = (const float*)d_in[23];
  const float* pe_w   = (const float*)d_in[24], *pe_b   = (const float*)d_in[25];
  const float* up_w   = (const float*)d_in[26], *up_b   = (const float*)d_in[27];
  const float* ag_q_w = (const float*)d_in[28], *ag_q_b = (const float*)d_in[29];
  const float* ag_k_w = (const float*)d_in[30], *ag_k_b = (const float*)d_in[31];
  const float* ag_v_w = (const float*)d_in[32], *ag_v_b = (const float*)d_in[33];
  const float* ag_o_w = (const float*)d_in[34], *ag_o_b = (const float*)d_in[35];
  const float* ar_q_w = (const float*)d_in[36], *ar_q_b = (const float*)d_in[37];
  const float* ar_k_w = (const float*)d_in[38], *ar_k_b = (const float*)d_in[39];
  const float* ar_v_w = (const float*)d_in[40], *ar_v_b = (const float*)d_in[41];
  const float* ar_o_w = (const float*)d_in[42], *ar_o_b = (const float*)d_in[43];

  float* out = (float*)d_out;          // g_out (25165824 f) then up (50331648 f)
  float* ws = (float*)d_ws;
  size_t off = 0;
  auto A = [&](size_t n) { float* p = ws + off; off += n; return p; };
  float* q_g   = A(12288);   float* q_r   = A(12288);
  float* Wk_g  = A(16384);   float* bk_g  = A(128);
  float* Wv_g  = A(16384);   float* bv_g  = A(128);
  float* Wk_r  = A(16384);   float* bk_r  = A(128);
  float* Wv_r  = A(16384);   float* bv_r  = A(128);
  float* Wvo_g = A(65536);   float* bvo_g = A(128);
  float* Wvo_r = A(65536);   float* bvo_r = A(128);
  float* ck_g  = A(384);     float* ck_r  = A(384);
  u16*   PkT_g = (u16*)A(26112);   // 4*96*136 bf16
  u16*   PkT_r = (u16*)A(26112);
  u16*   W1c_g = (u16*)A(8192);    // 256*64 bf16
  u16*   W1c_r = (u16*)A(16384);   // 256*128 bf16
  u16*   peB   = (u16*)A(524288);  // 128*8192 bf16
  float* lP_g  = A(12288);   float* lP_r  = A(3072);
  float* og_g  = A(12288);   float* og_r  = A(12288);
  u16*   accP_g = (u16*)A(786432);    // 4*32*12288 bf16
  u16*   patchP = (u16*)A(3145728);   // 8*6144*128 bf16
  u16*   accP_r = (u16*)A(196608);    // 4*8*12288 bf16

  k_pre1<<<2148, 128, 0, stream>>>(
      gek_w1, gev_w1, rk_w1, rv_w1, W1c_g, W1c_r,
      pe_w, peB,
      gti, te_w1, te_b1, te_w2, te_b2, ag_q_w, ag_q_b, ar_q_w, ar_q_b, q_g, q_r,
      gek_w2, gek_b2, ag_k_w, ag_k_b, Wk_g, bk_g,
      gev_w2, gev_b2, ag_v_w, ag_v_b, Wv_g, bv_g,
      rk_w2,  rk_b2,  ar_k_w, ar_k_b, Wk_r, bk_r,
      rv_w2,  rv_b2,  ar_v_w, ar_v_b, Wv_r, bv_r);
  k_wvopk<<<dim3(129, 16), 128, 0, stream>>>(
      Wv_g, bv_g, ag_o_w, ag_o_b, Wvo_g, bvo_g,
      Wv_r, bv_r, ar_o_w, ar_o_b, Wvo_r, bvo_r,
      Wk_g, bk_g, q_g, PkT_g, ck_g,
      Wk_r, bk_r, q_r, PkT_r, ck_r);

  // K3: graph flash (128 blocks x 24 tiles) || patch conv (768 blocks)
  k_big1<<<896, 256, 0, stream>>>(
      gf, W1c_g, gek_b1, gev_b1, PkT_g, ck_g, accP_g, lP_g,
      gridf, peB, patchP);
  // K4: graph chunk-reduce+og (96) || grid flash (32 blocks x 3 tiles)
  k_big2<<<128, 256, 0, stream>>>(
      accP_g, lP_g, Wvo_g, bvo_g, og_g,
      patchP, pe_b, W1c_r, rk_b1, rv_b1, PkT_r, ck_r, accP_r, lP_r);
  // K5: grid chunk-reduce+og (96) || g_out writer (4096)
  k_big3<<<4192, 256, 0, stream>>>(
      accP_r, lP_r, Wvo_r, bvo_r, og_r, og_g, out);
  // K6: U-GEMM + upsample writer
  k_upfuse<<<512, 256, 0, stream>>>(og_r, up_w, up_b, out + 25165824);
}